// Round 5
// baseline (1557.917 us; speedup 1.0000x reference)
//
#include <hip/hip_runtime.h>

#define NN  50000
#define NE  600000
#define CC  128
#define NFF 256
#define ECH 64
#define EIN 192   // ECH + CC

typedef __attribute__((ext_vector_type(8))) short bf16x8;
typedef __attribute__((ext_vector_type(4))) short bf16x4;
typedef __attribute__((ext_vector_type(4))) float f32x4;

__device__ __forceinline__ float sspf(float v) {
    float sp = (v > 0.0f) ? (v + log1pf(__expf(-v))) : log1pf(__expf(v));
    return sp - 0.693147180559945f;
}
__device__ __forceinline__ short bf16r(float f) {
    unsigned u = __float_as_uint(f);
    u = (u + 0x7FFFu + ((u >> 16) & 1u)) >> 16;
    return (short)u;
}
__device__ __forceinline__ float bf2f(short s) {
    unsigned u = ((unsigned)(unsigned short)s) << 16;
    return __uint_as_float(u);
}

// ---- pack weights to bf16 fragment-linear layout for mfma_16x16x32 B-operand
__global__ void kpack(const float* __restrict__ Wf1, const float* __restrict__ Wf2,
                      const float* __restrict__ We, short* __restrict__ p) {
    int i = blockIdx.x * 256 + threadIdx.x;
    if (i < 16384) {                       // Wf1 [64][256]
        int j = i & 7, lane = (i >> 3) & 63, n16 = (i >> 9) & 15, ks = i >> 13;
        int k = ks * 32 + (lane >> 4) * 8 + j, col = n16 * 16 + (lane & 15);
        p[i] = bf16r(Wf1[k * NFF + col]);
    } else if (i < 16384 + 65536) {        // Wf2 [256][256]
        int t = i - 16384;
        int j = t & 7, lane = (t >> 3) & 63, n16 = (t >> 9) & 15, ks = t >> 13;
        int k = ks * 32 + (lane >> 4) * 8 + j, col = n16 * 16 + (lane & 15);
        p[i] = bf16r(Wf2[k * NFF + col]);
    } else if (i < 16384 + 65536 + 24576) { // We [192][128]
        int t = i - 81920;
        int j = t & 7, lane = (t >> 3) & 63, n16 = (t >> 9) & 7, ks = t >> 12;
        int k = ks * 32 + (lane >> 4) * 8 + j, col = n16 * 16 + (lane & 15);
        p[i] = bf16r(We[k * CC + col]);
    }
}

// ---- K0: zero a float4-multiple region ----
__global__ void k0_zero(float* __restrict__ p, long n4) {
    long i = (long)blockIdx.x * blockDim.x + threadIdx.x;
    long stride = (long)gridDim.x * blockDim.x;
    float4 z = {0.f, 0.f, 0.f, 0.f};
    for (; i < n4; i += stride) ((float4*)p)[i] = z;
}

// ---- counting sort by destination row ----
__global__ void k_cnt(const int* __restrict__ eidx, int* __restrict__ cnt) {
    int e = blockIdx.x * 256 + threadIdx.x;
    if (e < NE) atomicAdd(&cnt[eidx[e]], 1);
}

// single-block exclusive scan over cnt[NN] -> offw[NN]; 1024 threads
__global__ __launch_bounds__(1024) void k_scan(const int* __restrict__ cnt,
                                               int* __restrict__ offw) {
    __shared__ int sw[16];
    __shared__ int carry;
    int lane = threadIdx.x & 63, wv = threadIdx.x >> 6;
    if (threadIdx.x == 0) carry = 0;
    __syncthreads();
    for (int base = 0; base < NN; base += 1024) {
        int i = base + (int)threadIdx.x;
        int v = (i < NN) ? cnt[i] : 0;
        int inc = v;
        #pragma unroll
        for (int d = 1; d < 64; d <<= 1) {
            int t = __shfl_up(inc, d, 64);
            if (lane >= d) inc += t;
        }
        if (lane == 63) sw[wv] = inc;
        __syncthreads();
        int woff = 0;
        #pragma unroll
        for (int k = 0; k < 16; ++k) woff += (k < wv) ? sw[k] : 0;
        if (i < NN) offw[i] = carry + woff + inc - v;
        __syncthreads();
        if (threadIdx.x == 0) {
            int tot = 0;
            #pragma unroll
            for (int k = 0; k < 16; ++k) tot += sw[k];
            carry += tot;
        }
        __syncthreads();
    }
}

// ---- scatter: physically permute edges into row-sorted order ----
// writes row_s/col_s and ea_s (bf16, 128B per edge) at the sorted position
__global__ void k_scatter(const int* __restrict__ eidx, const float* __restrict__ ea,
                          int* __restrict__ offw,
                          int* __restrict__ row_s, int* __restrict__ col_s,
                          short* __restrict__ ea_s) {
    int e = blockIdx.x * 256 + threadIdx.x;
    if (e >= NE) return;
    int r = eidx[e], c = eidx[NE + e];
    int pos = atomicAdd(&offw[r], 1);
    row_s[pos] = r;
    col_s[pos] = c;
    const float4* src = (const float4*)(ea + (size_t)e * ECH);
    short* dst = ea_s + (size_t)pos * ECH;
    #pragma unroll
    for (int i = 0; i < 8; ++i) {
        float4 f0 = src[2 * i], f1 = src[2 * i + 1];
        bf16x8 v = {bf16r(f0.x), bf16r(f0.y), bf16r(f0.z), bf16r(f0.w),
                    bf16r(f1.x), bf16r(f1.y), bf16r(f1.z), bf16r(f1.w)};
        *(bf16x8*)(dst + i * 8) = v;
    }
}

// ---- K1: h[N,NF] = x[N,C] @ W_lin1[C,NF], output bf16 ----
__global__ __launch_bounds__(256) void k1_h(const float* __restrict__ x,
                                            const float* __restrict__ W,
                                            short* __restrict__ h) {
    __shared__ __align__(16) float xs[16][CC];
    int n0 = blockIdx.x * 16;
    int tid = threadIdx.x;
    for (int i = tid; i < 16 * CC / 4; i += 256) {
        int nd = i >> 5;
        int c4 = i & 31;
        *(float4*)&xs[nd][c4 * 4] = ((const float4*)x)[(size_t)(n0 + nd) * 32 + c4];
    }
    __syncthreads();
    int j0 = (tid & 63) * 4;
    int i0 = (tid >> 6) * 4;
    float acc[4][4] = {};
    #pragma unroll 4
    for (int k = 0; k < CC; ++k) {
        float4 b = *(const float4*)&W[k * NFF + j0];
        #pragma unroll
        for (int i = 0; i < 4; ++i) {
            float a = xs[i0 + i][k];
            acc[i][0] = fmaf(a, b.x, acc[i][0]);
            acc[i][1] = fmaf(a, b.y, acc[i][1]);
            acc[i][2] = fmaf(a, b.z, acc[i][2]);
            acc[i][3] = fmaf(a, b.w, acc[i][3]);
        }
    }
    #pragma unroll
    for (int i = 0; i < 4; ++i) {
        bf16x4 v = {bf16r(acc[i][0]), bf16r(acc[i][1]), bf16r(acc[i][2]), bf16r(acc[i][3])};
        *(bf16x4*)&h[(size_t)(n0 + i0 + i) * NFF + j0] = v;
    }
}

// ---- K2: MFMA fused filter-net + LDS-staged gather + merged scatter-add ----
// block = 256 thr (4 waves), 32 sorted edges; wave w owns cols [w*64, w*64+64)
// grid = 18752 (8 XCD chunks of 2344); last 2 logical blocks are dummies.
__global__ __launch_bounds__(256, 8) void k2_mfma(
        const short* __restrict__ ea_s, const int* __restrict__ row_s,
        const int* __restrict__ col_s,
        const short* __restrict__ pWf1, const float* __restrict__ bf1v,
        const short* __restrict__ pWf2, const float* __restrict__ bf2v,
        const short* __restrict__ h, float* __restrict__ agg) {
    __shared__ char t1S[32 * 512];   // t1 (swizzled); reused for staged h rows
    __shared__ int rowS[32], colS[32];
    // chunked XCD swizzle: consecutive logical tiles share an XCD L2
    int lbid = (blockIdx.x & 7) * 2344 + (blockIdx.x >> 3);
    int e0 = lbid * 32;
    if (e0 >= NE) return;
    int tid = threadIdx.x;
    int lane = tid & 63, w = tid >> 6;
    int q = lane >> 4, l15 = lane & 15;

    if (tid < 32) {
        rowS[tid] = row_s[e0 + tid];
        colS[tid] = col_s[e0 + tid];
    }

    f32x4 acc[2][4];
    #pragma unroll
    for (int mf = 0; mf < 2; ++mf)
        #pragma unroll
        for (int nf = 0; nf < 4; ++nf) acc[mf][nf] = f32x4{0.f, 0.f, 0.f, 0.f};

    // phase 1: t1 = ssp(ea_s @ Wf1 + b1), K=64, M=32. A direct from global bf16.
    #pragma unroll
    for (int ks = 0; ks < 2; ++ks) {
        bf16x8 a[2];
        #pragma unroll
        for (int mf = 0; mf < 2; ++mf)
            a[mf] = *(const bf16x8*)(ea_s + (size_t)(e0 + mf * 16 + l15) * ECH + ks * 32 + q * 8);
        #pragma unroll
        for (int nf = 0; nf < 4; ++nf) {
            bf16x8 b = *(const bf16x8*)(pWf1 + (((ks * 16 + w * 4 + nf) * 64) + lane) * 8);
            #pragma unroll
            for (int mf = 0; mf < 2; ++mf)
                acc[mf][nf] = __builtin_amdgcn_mfma_f32_16x16x32_bf16(a[mf], b, acc[mf][nf], 0, 0, 0);
        }
    }
    // ssp + bias, write t1 (bf16, swizzled). C/D: col=lane&15, row=(lane>>4)*4+r
    #pragma unroll
    for (int nf = 0; nf < 4; ++nf) {
        int col = w * 64 + nf * 16 + l15;
        float bias = bf1v[col];
        #pragma unroll
        for (int mf = 0; mf < 2; ++mf) {
            #pragma unroll
            for (int r = 0; r < 4; ++r) {
                int row = mf * 16 + q * 4 + r;
                *(short*)(t1S + row * 512 + ((col * 2) ^ ((row & 7) << 4))) =
                    bf16r(sspf(acc[mf][nf][r] + bias));
            }
        }
    }
    __syncthreads();

    #pragma unroll
    for (int mf = 0; mf < 2; ++mf)
        #pragma unroll
        for (int nf = 0; nf < 4; ++nf) acc[mf][nf] = f32x4{0.f, 0.f, 0.f, 0.f};

    // phase 2: Wf = t1 @ Wf2 + b2, K=256, M=32
    for (int ks = 0; ks < 8; ++ks) {
        bf16x8 a[2];
        #pragma unroll
        for (int mf = 0; mf < 2; ++mf) {
            int row = mf * 16 + l15;
            a[mf] = *(const bf16x8*)(t1S + row * 512 + ((ks * 64 + q * 16) ^ ((row & 7) << 4)));
        }
        #pragma unroll
        for (int nf = 0; nf < 4; ++nf) {
            bf16x8 b = *(const bf16x8*)(pWf2 + (((ks * 16 + w * 4 + nf) * 64) + lane) * 8);
            #pragma unroll
            for (int mf = 0; mf < 2; ++mf)
                acc[mf][nf] = __builtin_amdgcn_mfma_f32_16x16x32_bf16(a[mf], b, acc[mf][nf], 0, 0, 0);
        }
    }
    __syncthreads();   // t1S reads complete; region now reused for h rows

    // stage h[colS[0..31]] into LDS: 8 threads/row, full 128B lines per load
    {
        int r = tid >> 3, ch = tid & 7;
        const short* hp = h + (size_t)colS[r] * NFF;
        int sw = (r & 7) << 4;
        #pragma unroll
        for (int i = 0; i < 4; ++i) {
            bf16x8 v = *(const bf16x8*)(hp + i * 64 + ch * 8);
            *(bf16x8*)(t1S + r * 512 + ((i * 128 + ch * 16) ^ sw)) = v;
        }
    }
    __syncthreads();

    // epilogue: read h from LDS, modulate, run-length-merged scatter-add
    #pragma unroll
    for (int nf = 0; nf < 4; ++nf) {
        int col = w * 64 + nf * 16 + l15;
        float bias = bf2v[col];
        #pragma unroll
        for (int mf = 0; mf < 2; ++mf) {
            int ebase = mf * 16 + q * 4;
            float sum = 0.f;
            int prow = rowS[ebase];
            #pragma unroll
            for (int r = 0; r < 4; ++r) {
                int eloc = ebase + r;
                float wf = acc[mf][nf][r] + bias;
                float hv = bf2f(*(const short*)(t1S + eloc * 512 + ((col * 2) ^ ((eloc & 7) << 4))));
                int rw = rowS[eloc];
                if (rw != prow) {
                    atomicAdd(&agg[(size_t)prow * NFF + col], sum);
                    sum = 0.f;
                    prow = rw;
                }
                sum = fmaf(hv, wf, sum);
            }
            atomicAdd(&agg[(size_t)prow * NFF + col], sum);
        }
    }
}

// ---- K3: x_out = relu(ssp(agg@Wl2+b2)@Wl3+b3) + x ----
__global__ __launch_bounds__(128) void k3_node(
        const float* __restrict__ agg,
        const float* __restrict__ Wl2, const float* __restrict__ bl2,
        const float* __restrict__ Wl3, const float* __restrict__ bl3,
        const float* __restrict__ x, float* __restrict__ xo) {
    __shared__ __align__(16) float as[16][NFF];
    __shared__ __align__(16) float t2[16][CC];
    int n0 = blockIdx.x * 16;
    int tid = threadIdx.x;
    for (int i = tid; i < 16 * NFF / 4; i += 128) {
        int nd = i >> 6;
        int c4 = i & 63;
        *(float4*)&as[nd][c4 * 4] = ((const float4*)agg)[(size_t)(n0 + nd) * 64 + c4];
    }
    __syncthreads();
    int j0 = (tid & 31) * 4;
    int i0 = (tid >> 5) * 4;

    float acc[4][4] = {};
    #pragma unroll 4
    for (int k = 0; k < NFF; ++k) {
        float4 b = *(const float4*)&Wl2[k * CC + j0];
        #pragma unroll
        for (int i = 0; i < 4; ++i) {
            float a = as[i0 + i][k];
            acc[i][0] = fmaf(a, b.x, acc[i][0]);
            acc[i][1] = fmaf(a, b.y, acc[i][1]);
            acc[i][2] = fmaf(a, b.z, acc[i][2]);
            acc[i][3] = fmaf(a, b.w, acc[i][3]);
        }
    }
    float4 b2v = *(const float4*)&bl2[j0];
    #pragma unroll
    for (int i = 0; i < 4; ++i) {
        float4 v;
        v.x = sspf(acc[i][0] + b2v.x);
        v.y = sspf(acc[i][1] + b2v.y);
        v.z = sspf(acc[i][2] + b2v.z);
        v.w = sspf(acc[i][3] + b2v.w);
        *(float4*)&t2[i0 + i][j0] = v;
    }
    __syncthreads();

    float acc3[4][4] = {};
    #pragma unroll 4
    for (int k = 0; k < CC; ++k) {
        float4 b = *(const float4*)&Wl3[k * CC + j0];
        #pragma unroll
        for (int i = 0; i < 4; ++i) {
            float a = t2[i0 + i][k];
            acc3[i][0] = fmaf(a, b.x, acc3[i][0]);
            acc3[i][1] = fmaf(a, b.y, acc3[i][1]);
            acc3[i][2] = fmaf(a, b.z, acc3[i][2]);
            acc3[i][3] = fmaf(a, b.w, acc3[i][3]);
        }
    }
    float4 b3v = *(const float4*)&bl3[j0];
    #pragma unroll
    for (int i = 0; i < 4; ++i) {
        size_t base = (size_t)(n0 + i0 + i) * CC + j0;
        float4 xv = *(const float4*)&x[base];
        float4 v;
        v.x = fmaxf(acc3[i][0] + b3v.x, 0.f) + xv.x;
        v.y = fmaxf(acc3[i][1] + b3v.y, 0.f) + xv.y;
        v.z = fmaxf(acc3[i][2] + b3v.z, 0.f) + xv.z;
        v.w = fmaxf(acc3[i][3] + b3v.w, 0.f) + xv.w;
        *(float4*)&xo[base] = v;
    }
}

// ---- K4: MFMA e_out = tanh([ea | xo[row]+xo[col]] @ We + be), K=192, N=128 ----
__global__ __launch_bounds__(256) void k4_mfma(
        const float* __restrict__ ea, const int* __restrict__ eidx,
        const float* __restrict__ xo, const short* __restrict__ pWe,
        const float* __restrict__ bev, float* __restrict__ eo) {
    __shared__ char aS[64 * 384];    // [64][192] bf16, stride 384B, XOR-swizzled
    int e0 = blockIdx.x * 64;
    int tid = threadIdx.x;
    int lane = tid & 63, w = tid >> 6;
    int q = lane >> 4, l15 = lane & 15;

    {   // stage ea (k 0..63)
        int r = tid >> 2, cp = tid & 3;
        const float4* src = (const float4*)(ea + (size_t)(e0 + r) * ECH + cp * 16);
        float4 f0 = src[0], f1 = src[1], f2 = src[2], f3 = src[3];
        bf16x8 c0 = {bf16r(f0.x), bf16r(f0.y), bf16r(f0.z), bf16r(f0.w),
                     bf16r(f1.x), bf16r(f1.y), bf16r(f1.z), bf16r(f1.w)};
        bf16x8 c1 = {bf16r(f2.x), bf16r(f2.y), bf16r(f2.z), bf16r(f2.w),
                     bf16r(f3.x), bf16r(f3.y), bf16r(f3.z), bf16r(f3.w)};
        int sw = (r & 7) << 4;
        *(bf16x8*)(aS + r * 384 + ((cp * 32) ^ sw)) = c0;
        *(bf16x8*)(aS + r * 384 + ((cp * 32 + 16) ^ sw)) = c1;
    }
    {   // stage xo[row]+xo[col] (k 64..191)
        int e = tid >> 2, p = tid & 3;
        int rr = eidx[e0 + e], cc = eidx[NE + e0 + e];
        const float4* xr = (const float4*)(xo + (size_t)rr * CC);
        const float4* xc = (const float4*)(xo + (size_t)cc * CC);
        int sw = (e & 7) << 4;
        #pragma unroll
        for (int it = 0; it < 8; ++it) {
            int fi = p + it * 4;
            float4 va = xr[fi], vb = xc[fi];
            bf16x4 hv = {bf16r(va.x + vb.x), bf16r(va.y + vb.y),
                         bf16r(va.z + vb.z), bf16r(va.w + vb.w)};
            int byte = (ECH + fi * 4) * 2;
            *(bf16x4*)(aS + e * 384 + (byte ^ sw)) = hv;
        }
    }
    __syncthreads();

    f32x4 acc[8];
    #pragma unroll
    for (int nf = 0; nf < 8; ++nf) acc[nf] = f32x4{0.f, 0.f, 0.f, 0.f};

    #pragma unroll
    for (int ks = 0; ks < 6; ++ks) {
        int row = w * 16 + l15;
        bf16x8 a = *(const bf16x8*)(aS + row * 384 + ((ks * 64 + q * 16) ^ ((row & 7) << 4)));
        #pragma unroll
        for (int nf = 0; nf < 8; ++nf) {
            bf16x8 b = *(const bf16x8*)(pWe + (((ks * 8 + nf) * 64) + lane) * 8);
            acc[nf] = __builtin_amdgcn_mfma_f32_16x16x32_bf16(a, b, acc[nf], 0, 0, 0);
        }
    }
    #pragma unroll
    for (int nf = 0; nf < 8; ++nf) {
        int col = nf * 16 + l15;
        float bias = bev[col];
        #pragma unroll
        for (int r = 0; r < 4; ++r) {
            int e = e0 + w * 16 + q * 4 + r;
            eo[(size_t)e * CC + col] = tanhf(acc[nf][r] + bias);
        }
    }
}

extern "C" void kernel_launch(void* const* d_in, const int* in_sizes, int n_in,
                              void* d_out, int out_size, void* d_ws, size_t ws_size,
                              hipStream_t stream) {
    const float* x   = (const float*)d_in[0];
    const int*   ei  = (const int*)d_in[1];
    const float* ea  = (const float*)d_in[2];
    const float* Wf1 = (const float*)d_in[4];
    const float* bf1 = (const float*)d_in[5];
    const float* Wf2 = (const float*)d_in[6];
    const float* bf2 = (const float*)d_in[7];
    const float* Wl1 = (const float*)d_in[8];
    const float* Wl2 = (const float*)d_in[9];
    const float* bl2 = (const float*)d_in[10];
    const float* Wl3 = (const float*)d_in[11];
    const float* bl3 = (const float*)d_in[12];
    const float* We  = (const float*)d_in[13];
    const float* be  = (const float*)d_in[14];

    float* xo = (float*)d_out;                 // [N, C]
    float* eo = xo + (size_t)NN * CC;          // [E, C]

    // ws: [packed weights][agg fp32 51.2MB]
    short* pW   = (short*)d_ws;
    short* pWf1 = pW;
    short* pWf2 = pW + 16384;
    short* pWe  = pW + 81920;
    float* agg  = (float*)((char*)d_ws + 262144);
    size_t one  = (size_t)NN * NFF;

    // scratch carved from the TAIL of the e_out region (written only by K4 at
    // the very end). All regions fully (re)written every call before use.
    char* top   = (char*)d_out + (size_t)out_size * sizeof(float);
    short* h    = (short*)(top - 25600000);              // NN*NFF*2
    short* ea_s = (short*)((char*)h - 76800000);         // NE*ECH*2
    int* row_s  = (int*)((char*)ea_s - 2400000);         // NE*4
    int* col_s  = (int*)((char*)row_s - 2400000);        // NE*4
    int* cnt    = (int*)((char*)col_s - 200704);
    int* offw   = (int*)((char*)cnt - 200704);

    kpack<<<416, 256, 0, stream>>>(Wf1, Wf2, We, pW);
    k0_zero<<<1024, 256, 0, stream>>>(agg, (long)(one / 4));
    k0_zero<<<49, 256, 0, stream>>>((float*)cnt, 12500);
    k_cnt<<<(NE + 255) / 256, 256, 0, stream>>>(ei, cnt);
    k_scan<<<1, 1024, 0, stream>>>(cnt, offw);
    k_scatter<<<(NE + 255) / 256, 256, 0, stream>>>(ei, ea, offw, row_s, col_s, ea_s);
    k1_h<<<NN / 16, 256, 0, stream>>>(x, Wl1, h);
    k2_mfma<<<18752, 256, 0, stream>>>(ea_s, row_s, col_s, pWf1, bf1, pWf2, bf2, h, agg);
    k3_node<<<NN / 16, 128, 0, stream>>>(agg, Wl2, bl2, Wl3, bl3, x, xo);
    k4_mfma<<<NE / 64, 256, 0, stream>>>(ea, ei, xo, pWe, be, eo);
}

// Round 6
// 838.797 us; speedup vs baseline: 1.8573x; 1.8573x over previous
//
#include <hip/hip_runtime.h>

#define NN  50000
#define NE  600000
#define CC  128
#define NFF 256
#define ECH 64
#define EIN 192   // ECH + CC

typedef __attribute__((ext_vector_type(8))) short bf16x8;
typedef __attribute__((ext_vector_type(4))) short bf16x4;
typedef __attribute__((ext_vector_type(4))) float f32x4;

// fast shifted-softplus: softplus(v)-ln2 via hw exp/log (err ~1e-6, bf16-safe)
__device__ __forceinline__ float sspf(float v) {
    float e = __expf(-fabsf(v));
    return fmaxf(v, 0.f) + __logf(1.f + e) - 0.693147180559945f;
}
__device__ __forceinline__ short bf16r(float f) {
    unsigned u = __float_as_uint(f);
    u = (u + 0x7FFFu + ((u >> 16) & 1u)) >> 16;
    return (short)u;
}
__device__ __forceinline__ float bf2f(short s) {
    unsigned u = ((unsigned)(unsigned short)s) << 16;
    return __uint_as_float(u);
}

// ---- pack weights to bf16 fragment-linear layout for mfma_16x16x32 B-operand
__global__ void kpack(const float* __restrict__ Wf1, const float* __restrict__ Wf2,
                      const float* __restrict__ We, short* __restrict__ p) {
    int i = blockIdx.x * 256 + threadIdx.x;
    if (i < 16384) {                       // Wf1 [64][256]
        int j = i & 7, lane = (i >> 3) & 63, n16 = (i >> 9) & 15, ks = i >> 13;
        int k = ks * 32 + (lane >> 4) * 8 + j, col = n16 * 16 + (lane & 15);
        p[i] = bf16r(Wf1[k * NFF + col]);
    } else if (i < 16384 + 65536) {        // Wf2 [256][256]
        int t = i - 16384;
        int j = t & 7, lane = (t >> 3) & 63, n16 = (t >> 9) & 15, ks = t >> 13;
        int k = ks * 32 + (lane >> 4) * 8 + j, col = n16 * 16 + (lane & 15);
        p[i] = bf16r(Wf2[k * NFF + col]);
    } else if (i < 16384 + 65536 + 24576) { // We [192][128]
        int t = i - 81920;
        int j = t & 7, lane = (t >> 3) & 63, n16 = (t >> 9) & 7, ks = t >> 12;
        int k = ks * 32 + (lane >> 4) * 8 + j, col = n16 * 16 + (lane & 15);
        p[i] = bf16r(We[k * CC + col]);
    }
}

// ---- K0: zero a float4-multiple region ----
__global__ void k0_zero(float* __restrict__ p, long n4) {
    long i = (long)blockIdx.x * blockDim.x + threadIdx.x;
    long stride = (long)gridDim.x * blockDim.x;
    float4 z = {0.f, 0.f, 0.f, 0.f};
    for (; i < n4; i += stride) ((float4*)p)[i] = z;
}

// ---- CSR build: count, scan (offw mutable + rowptr pristine), scatter perm ----
__global__ void k_cnt(const int* __restrict__ eidx, int* __restrict__ cnt) {
    int e = blockIdx.x * 256 + threadIdx.x;
    if (e < NE) atomicAdd(&cnt[eidx[e]], 1);
}

__global__ __launch_bounds__(1024) void k_scan(const int* __restrict__ cnt,
                                               int* __restrict__ offw,
                                               int* __restrict__ rowptr) {
    __shared__ int sw[16];
    __shared__ int carry;
    int lane = threadIdx.x & 63, wv = threadIdx.x >> 6;
    if (threadIdx.x == 0) carry = 0;
    __syncthreads();
    for (int base = 0; base < NN; base += 1024) {
        int i = base + (int)threadIdx.x;
        int v = (i < NN) ? cnt[i] : 0;
        int inc = v;
        #pragma unroll
        for (int d = 1; d < 64; d <<= 1) {
            int t = __shfl_up(inc, d, 64);
            if (lane >= d) inc += t;
        }
        if (lane == 63) sw[wv] = inc;
        __syncthreads();
        int woff = 0;
        #pragma unroll
        for (int k = 0; k < 16; ++k) woff += (k < wv) ? sw[k] : 0;
        if (i < NN) {
            int ex = carry + woff + inc - v;
            offw[i] = ex;
            rowptr[i] = ex;
        }
        __syncthreads();
        if (threadIdx.x == 0) {
            int tot = 0;
            #pragma unroll
            for (int k = 0; k < 16; ++k) tot += sw[k];
            carry += tot;
        }
        __syncthreads();
    }
    if (threadIdx.x == 0) rowptr[NN] = carry;   // == NE
}

__global__ void k_scatter(const int* __restrict__ eidx, int* __restrict__ offw,
                          int* __restrict__ perm) {
    int e = blockIdx.x * 256 + threadIdx.x;
    if (e < NE) {
        int pos = atomicAdd(&offw[eidx[e]], 1);
        perm[pos] = e;
    }
}

// ---- K1: h[N,NF] = x[N,C] @ W_lin1[C,NF], output bf16 ----
__global__ __launch_bounds__(256) void k1_h(const float* __restrict__ x,
                                            const float* __restrict__ W,
                                            short* __restrict__ h) {
    __shared__ __align__(16) float xs[16][CC];
    int n0 = blockIdx.x * 16;
    int tid = threadIdx.x;
    for (int i = tid; i < 16 * CC / 4; i += 256) {
        int nd = i >> 5;
        int c4 = i & 31;
        *(float4*)&xs[nd][c4 * 4] = ((const float4*)x)[(size_t)(n0 + nd) * 32 + c4];
    }
    __syncthreads();
    int j0 = (tid & 63) * 4;
    int i0 = (tid >> 6) * 4;
    float acc[4][4] = {};
    #pragma unroll 4
    for (int k = 0; k < CC; ++k) {
        float4 b = *(const float4*)&W[k * NFF + j0];
        #pragma unroll
        for (int i = 0; i < 4; ++i) {
            float a = xs[i0 + i][k];
            acc[i][0] = fmaf(a, b.x, acc[i][0]);
            acc[i][1] = fmaf(a, b.y, acc[i][1]);
            acc[i][2] = fmaf(a, b.z, acc[i][2]);
            acc[i][3] = fmaf(a, b.w, acc[i][3]);
        }
    }
    #pragma unroll
    for (int i = 0; i < 4; ++i) {
        bf16x4 v = {bf16r(acc[i][0]), bf16r(acc[i][1]), bf16r(acc[i][2]), bf16r(acc[i][3])};
        *(bf16x4*)&h[(size_t)(n0 + i0 + i) * NFF + j0] = v;
    }
}

// ---- K2a: MFMA filter-net + modulate -> streaming msg write (NO atomics) ----
// block = 256 thr (4 waves), 32 edges; wave w owns cols [w*64, w*64+64)
__global__ __launch_bounds__(256, 8) void k2a_msg(
        const float* __restrict__ ea, const int* __restrict__ eidx,
        const short* __restrict__ pWf1, const float* __restrict__ bf1v,
        const short* __restrict__ pWf2, const float* __restrict__ bf2v,
        const short* __restrict__ h, short* __restrict__ msg) {
    __shared__ char eaS[32 * 128];   // [32][64] bf16, swizzled
    __shared__ char t1S[32 * 512];   // t1 (swizzled); reused for staged h rows
    __shared__ int colS[32];
    int e0 = blockIdx.x * 32;
    int tid = threadIdx.x;
    int lane = tid & 63, w = tid >> 6;
    int q = lane >> 4, l15 = lane & 15;

    if (tid < 32) colS[tid] = eidx[NE + e0 + tid];

    {   // stage ea -> bf16 swizzled LDS
        int r = tid >> 3, cp = tid & 7;
        const float4* src = (const float4*)(ea + (size_t)(e0 + r) * ECH + cp * 8);
        float4 f0 = src[0], f1 = src[1];
        bf16x8 c0 = {bf16r(f0.x), bf16r(f0.y), bf16r(f0.z), bf16r(f0.w),
                     bf16r(f1.x), bf16r(f1.y), bf16r(f1.z), bf16r(f1.w)};
        int sw = (r & 7) << 4;
        *(bf16x8*)(eaS + r * 128 + ((cp * 16) ^ sw)) = c0;
    }
    __syncthreads();

    f32x4 acc[2][4];
    #pragma unroll
    for (int mf = 0; mf < 2; ++mf)
        #pragma unroll
        for (int nf = 0; nf < 4; ++nf) acc[mf][nf] = f32x4{0.f, 0.f, 0.f, 0.f};

    // phase 1: t1 = ssp(ea @ Wf1 + b1), K=64, M=32
    #pragma unroll
    for (int ks = 0; ks < 2; ++ks) {
        bf16x8 a[2];
        #pragma unroll
        for (int mf = 0; mf < 2; ++mf) {
            int row = mf * 16 + l15;
            a[mf] = *(const bf16x8*)(eaS + row * 128 + ((ks * 64 + q * 16) ^ ((row & 7) << 4)));
        }
        #pragma unroll
        for (int nf = 0; nf < 4; ++nf) {
            bf16x8 b = *(const bf16x8*)(pWf1 + (((ks * 16 + w * 4 + nf) * 64) + lane) * 8);
            #pragma unroll
            for (int mf = 0; mf < 2; ++mf)
                acc[mf][nf] = __builtin_amdgcn_mfma_f32_16x16x32_bf16(a[mf], b, acc[mf][nf], 0, 0, 0);
        }
    }
    // ssp + bias, write t1 (bf16, swizzled). C/D: col=lane&15, row=(lane>>4)*4+r
    #pragma unroll
    for (int nf = 0; nf < 4; ++nf) {
        int col = w * 64 + nf * 16 + l15;
        float bias = bf1v[col];
        #pragma unroll
        for (int mf = 0; mf < 2; ++mf) {
            #pragma unroll
            for (int r = 0; r < 4; ++r) {
                int row = mf * 16 + q * 4 + r;
                *(short*)(t1S + row * 512 + ((col * 2) ^ ((row & 7) << 4))) =
                    bf16r(sspf(acc[mf][nf][r] + bias));
            }
        }
    }
    __syncthreads();

    #pragma unroll
    for (int mf = 0; mf < 2; ++mf)
        #pragma unroll
        for (int nf = 0; nf < 4; ++nf) acc[mf][nf] = f32x4{0.f, 0.f, 0.f, 0.f};

    // phase 2: Wf = t1 @ Wf2 + b2, K=256, M=32
    for (int ks = 0; ks < 8; ++ks) {
        bf16x8 a[2];
        #pragma unroll
        for (int mf = 0; mf < 2; ++mf) {
            int row = mf * 16 + l15;
            a[mf] = *(const bf16x8*)(t1S + row * 512 + ((ks * 64 + q * 16) ^ ((row & 7) << 4)));
        }
        #pragma unroll
        for (int nf = 0; nf < 4; ++nf) {
            bf16x8 b = *(const bf16x8*)(pWf2 + (((ks * 16 + w * 4 + nf) * 64) + lane) * 8);
            #pragma unroll
            for (int mf = 0; mf < 2; ++mf)
                acc[mf][nf] = __builtin_amdgcn_mfma_f32_16x16x32_bf16(a[mf], b, acc[mf][nf], 0, 0, 0);
        }
    }
    __syncthreads();   // t1S reads done; reuse for h rows

    // stage h[colS[0..31]] into LDS (coalesced 16B loads)
    {
        int r = tid >> 3, ch = tid & 7;
        const short* hp = h + (size_t)colS[r] * NFF;
        int sw = (r & 7) << 4;
        #pragma unroll
        for (int i = 0; i < 4; ++i) {
            bf16x8 v = *(const bf16x8*)(hp + i * 64 + ch * 8);
            *(bf16x8*)(t1S + r * 512 + ((i * 128 + ch * 16) ^ sw)) = v;
        }
    }
    __syncthreads();

    // epilogue: msg[e, col] = h[col_e, col] * Wf[e, col]  (streaming stores)
    #pragma unroll
    for (int nf = 0; nf < 4; ++nf) {
        int col = w * 64 + nf * 16 + l15;
        float bias = bf2v[col];
        #pragma unroll
        for (int mf = 0; mf < 2; ++mf) {
            #pragma unroll
            for (int r = 0; r < 4; ++r) {
                int eloc = mf * 16 + q * 4 + r;
                float wf = acc[mf][nf][r] + bias;
                float hv = bf2f(*(const short*)(t1S + eloc * 512 + ((col * 2) ^ ((eloc & 7) << 4))));
                msg[(size_t)(e0 + eloc) * NFF + col] = bf16r(hv * wf);
            }
        }
    }
}

// ---- K3 fused: agg = CSR-segment-sum(msg); x_out = relu(ssp(agg@Wl2+b2)@Wl3+b3)+x
__global__ __launch_bounds__(128) void k3_node(
        const short* __restrict__ msg, const int* __restrict__ perm,
        const int* __restrict__ rowptr,
        const float* __restrict__ Wl2, const float* __restrict__ bl2,
        const float* __restrict__ Wl3, const float* __restrict__ bl3,
        const float* __restrict__ x, float* __restrict__ xo) {
    __shared__ __align__(16) float as[16][NFF];
    __shared__ __align__(16) float t2[16][CC];
    int n0 = blockIdx.x * 16;
    int tid = threadIdx.x;

    {   // segment-sum prologue: 8 threads/node, thread owns 32 cols
        int nd = tid >> 3, c0 = (tid & 7) * 32;
        int n = n0 + nd;
        int p0 = rowptr[n], p1 = rowptr[n + 1];
        float a[32];
        #pragma unroll
        for (int i = 0; i < 32; ++i) a[i] = 0.f;
        for (int p = p0; p < p1; ++p) {
            int pe = perm[p];
            const short* mrow = msg + (size_t)pe * NFF + c0;
            #pragma unroll
            for (int j = 0; j < 4; ++j) {
                bf16x8 v = *(const bf16x8*)(mrow + j * 8);
                #pragma unroll
                for (int k = 0; k < 8; ++k) a[j * 8 + k] += bf2f(v[k]);
            }
        }
        #pragma unroll
        for (int j = 0; j < 8; ++j) {
            float4 v = {a[4 * j], a[4 * j + 1], a[4 * j + 2], a[4 * j + 3]};
            *(float4*)&as[nd][c0 + 4 * j] = v;
        }
    }
    __syncthreads();

    int j0 = (tid & 31) * 4;
    int i0 = (tid >> 5) * 4;

    float acc[4][4] = {};
    #pragma unroll 4
    for (int k = 0; k < NFF; ++k) {
        float4 b = *(const float4*)&Wl2[k * CC + j0];
        #pragma unroll
        for (int i = 0; i < 4; ++i) {
            float a = as[i0 + i][k];
            acc[i][0] = fmaf(a, b.x, acc[i][0]);
            acc[i][1] = fmaf(a, b.y, acc[i][1]);
            acc[i][2] = fmaf(a, b.z, acc[i][2]);
            acc[i][3] = fmaf(a, b.w, acc[i][3]);
        }
    }
    float4 b2v = *(const float4*)&bl2[j0];
    #pragma unroll
    for (int i = 0; i < 4; ++i) {
        float4 v;
        v.x = sspf(acc[i][0] + b2v.x);
        v.y = sspf(acc[i][1] + b2v.y);
        v.z = sspf(acc[i][2] + b2v.z);
        v.w = sspf(acc[i][3] + b2v.w);
        *(float4*)&t2[i0 + i][j0] = v;
    }
    __syncthreads();

    float acc3[4][4] = {};
    #pragma unroll 4
    for (int k = 0; k < CC; ++k) {
        float4 b = *(const float4*)&Wl3[k * CC + j0];
        #pragma unroll
        for (int i = 0; i < 4; ++i) {
            float a = t2[i0 + i][k];
            acc3[i][0] = fmaf(a, b.x, acc3[i][0]);
            acc3[i][1] = fmaf(a, b.y, acc3[i][1]);
            acc3[i][2] = fmaf(a, b.z, acc3[i][2]);
            acc3[i][3] = fmaf(a, b.w, acc3[i][3]);
        }
    }
    float4 b3v = *(const float4*)&bl3[j0];
    #pragma unroll
    for (int i = 0; i < 4; ++i) {
        size_t base = (size_t)(n0 + i0 + i) * CC + j0;
        float4 xv = *(const float4*)&x[base];
        float4 v;
        v.x = fmaxf(acc3[i][0] + b3v.x, 0.f) + xv.x;
        v.y = fmaxf(acc3[i][1] + b3v.y, 0.f) + xv.y;
        v.z = fmaxf(acc3[i][2] + b3v.z, 0.f) + xv.z;
        v.w = fmaxf(acc3[i][3] + b3v.w, 0.f) + xv.w;
        *(float4*)&xo[base] = v;
    }
}

// ---- K4: MFMA e_out = tanh([ea | xo[row]+xo[col]] @ We + be), K=192, N=128 ----
__global__ __launch_bounds__(256) void k4_mfma(
        const float* __restrict__ ea, const int* __restrict__ eidx,
        const float* __restrict__ xo, const short* __restrict__ pWe,
        const float* __restrict__ bev, float* __restrict__ eo) {
    __shared__ char aS[64 * 384];    // [64][192] bf16, swizzled
    int e0 = blockIdx.x * 64;
    int tid = threadIdx.x;
    int lane = tid & 63, w = tid >> 6;
    int q = lane >> 4, l15 = lane & 15;

    {   // stage ea (k 0..63)
        int r = tid >> 2, cp = tid & 3;
        const float4* src = (const float4*)(ea + (size_t)(e0 + r) * ECH + cp * 16);
        float4 f0 = src[0], f1 = src[1], f2 = src[2], f3 = src[3];
        bf16x8 c0 = {bf16r(f0.x), bf16r(f0.y), bf16r(f0.z), bf16r(f0.w),
                     bf16r(f1.x), bf16r(f1.y), bf16r(f1.z), bf16r(f1.w)};
        bf16x8 c1 = {bf16r(f2.x), bf16r(f2.y), bf16r(f2.z), bf16r(f2.w),
                     bf16r(f3.x), bf16r(f3.y), bf16r(f3.z), bf16r(f3.w)};
        int sw = (r & 7) << 4;
        *(bf16x8*)(aS + r * 384 + ((cp * 32) ^ sw)) = c0;
        *(bf16x8*)(aS + r * 384 + ((cp * 32 + 16) ^ sw)) = c1;
    }
    {   // stage xo[row]+xo[col] (k 64..191)
        int e = tid >> 2, p = tid & 3;
        int rr = eidx[e0 + e], cc = eidx[NE + e0 + e];
        const float4* xr = (const float4*)(xo + (size_t)rr * CC);
        const float4* xc = (const float4*)(xo + (size_t)cc * CC);
        int sw = (e & 7) << 4;
        #pragma unroll
        for (int it = 0; it < 8; ++it) {
            int fi = p + it * 4;
            float4 va = xr[fi], vb = xc[fi];
            bf16x4 hv = {bf16r(va.x + vb.x), bf16r(va.y + vb.y),
                         bf16r(va.z + vb.z), bf16r(va.w + vb.w)};
            int byte = (ECH + fi * 4) * 2;
            *(bf16x4*)(aS + e * 384 + (byte ^ sw)) = hv;
        }
    }
    __syncthreads();

    f32x4 acc[8];
    #pragma unroll
    for (int nf = 0; nf < 8; ++nf) acc[nf] = f32x4{0.f, 0.f, 0.f, 0.f};

    #pragma unroll
    for (int ks = 0; ks < 6; ++ks) {
        int row = w * 16 + l15;
        bf16x8 a = *(const bf16x8*)(aS + row * 384 + ((ks * 64 + q * 16) ^ ((row & 7) << 4)));
        #pragma unroll
        for (int nf = 0; nf < 8; ++nf) {
            bf16x8 b = *(const bf16x8*)(pWe + (((ks * 8 + nf) * 64) + lane) * 8);
            acc[nf] = __builtin_amdgcn_mfma_f32_16x16x32_bf16(a, b, acc[nf], 0, 0, 0);
        }
    }
    #pragma unroll
    for (int nf = 0; nf < 8; ++nf) {
        int col = nf * 16 + l15;
        float bias = bev[col];
        #pragma unroll
        for (int r = 0; r < 4; ++r) {
            int e = e0 + w * 16 + q * 4 + r;
            eo[(size_t)e * CC + col] = tanhf(acc[nf][r] + bias);
        }
    }
}

extern "C" void kernel_launch(void* const* d_in, const int* in_sizes, int n_in,
                              void* d_out, int out_size, void* d_ws, size_t ws_size,
                              hipStream_t stream) {
    const float* x   = (const float*)d_in[0];
    const int*   ei  = (const int*)d_in[1];
    const float* ea  = (const float*)d_in[2];
    const float* Wf1 = (const float*)d_in[4];
    const float* bf1 = (const float*)d_in[5];
    const float* Wf2 = (const float*)d_in[6];
    const float* bf2 = (const float*)d_in[7];
    const float* Wl1 = (const float*)d_in[8];
    const float* Wl2 = (const float*)d_in[9];
    const float* bl2 = (const float*)d_in[10];
    const float* Wl3 = (const float*)d_in[11];
    const float* bl3 = (const float*)d_in[12];
    const float* We  = (const float*)d_in[13];
    const float* be  = (const float*)d_in[14];

    float* xo = (float*)d_out;                 // [N, C] final
    float* eo = xo + (size_t)NN * CC;          // [E, C] final

    // region reuse (sequential lifetimes, fully rewritten every call):
    //   h   bf16 [N,256] lives in the xo region (dead before k3 writes xo)
    //   msg bf16 [E,256] lives in the eo region (dead before k4 writes eo)
    short* h   = (short*)xo;                   // 25.6 MB == N*C*4
    short* msg = (short*)eo;                   // 307.2 MB == E*C*4

    // ws: [packed weights 256KB][perm E][cnt N][offw N][rowptr N+1]  ~3.3 MB
    short* pW    = (short*)d_ws;
    short* pWf1  = pW;
    short* pWf2  = pW + 16384;
    short* pWe   = pW + 81920;
    int* perm    = (int*)((char*)d_ws + 262144);
    int* cnt     = perm + NE;
    int* offw    = cnt + NN;
    int* rowptr  = offw + NN;

    kpack<<<416, 256, 0, stream>>>(Wf1, Wf2, We, pW);
    k0_zero<<<49, 256, 0, stream>>>((float*)cnt, 12500);
    k_cnt<<<(NE + 255) / 256, 256, 0, stream>>>(ei, cnt);
    k_scan<<<1, 1024, 0, stream>>>(cnt, offw, rowptr);
    k_scatter<<<(NE + 255) / 256, 256, 0, stream>>>(ei, offw, perm);
    k1_h<<<NN / 16, 256, 0, stream>>>(x, Wl1, h);
    k2a_msg<<<NE / 32, 256, 0, stream>>>(ea, ei, pWf1, bf1, pWf2, bf2, h, msg);
    k3_node<<<NN / 16, 128, 0, stream>>>(msg, perm, rowptr, Wl2, bl2, Wl3, bl3, x, xo);
    k4_mfma<<<NE / 64, 256, 0, stream>>>(ea, ei, xo, pWe, be, eo);
}

// Round 7
// 601.228 us; speedup vs baseline: 2.5912x; 1.3951x over previous
//
#include <hip/hip_runtime.h>

#define NN  50000
#define NE  600000
#define CC  128
#define NFF 256
#define ECH 64
#define EIN 192   // ECH + CC

typedef __attribute__((ext_vector_type(8))) short bf16x8;
typedef __attribute__((ext_vector_type(4))) short bf16x4;
typedef __attribute__((ext_vector_type(4))) float f32x4;

// fast shifted-softplus: softplus(v)-ln2 via hw exp/log
__device__ __forceinline__ float sspf(float v) {
    float e = __expf(-fabsf(v));
    return fmaxf(v, 0.f) + __logf(1.f + e) - 0.693147180559945f;
}
// fast tanh via hw exp (err ~1e-7)
__device__ __forceinline__ float ftanh(float v) {
    float e = __expf(-2.f * fabsf(v));
    float r = (1.f - e) / (1.f + e);
    return copysignf(r, v);
}
__device__ __forceinline__ short bf16r(float f) {
    unsigned u = __float_as_uint(f);
    u = (u + 0x7FFFu + ((u >> 16) & 1u)) >> 16;
    return (short)u;
}
__device__ __forceinline__ float bf2f(short s) {
    unsigned u = ((unsigned)(unsigned short)s) << 16;
    return __uint_as_float(u);
}

// ---- pack ALL weights to bf16 fragment-linear layout for mfma_16x16x32 B-op
// packed[((ks*(N/16)+n16)*64 + lane)*8 + j] = B[ks*32+(lane>>4)*8+j][n16*16+(lane&15)]
#define PO_WF1 0
#define PO_WF2 16384
#define PO_WE  81920
#define PO_WL1 106496
#define PO_WL2 139264
#define PO_WL3 172032
#define P_TOT  188416
__global__ void kpack(const float* __restrict__ Wf1, const float* __restrict__ Wf2,
                      const float* __restrict__ We,  const float* __restrict__ Wl1,
                      const float* __restrict__ Wl2, const float* __restrict__ Wl3,
                      short* __restrict__ p) {
    int i = blockIdx.x * 256 + threadIdx.x;
    if (i < PO_WF2) {                      // Wf1 [64][256]
        int t = i - PO_WF1;
        int j = t & 7, lane = (t >> 3) & 63, n16 = (t >> 9) & 15, ks = t >> 13;
        p[i] = bf16r(Wf1[(ks * 32 + (lane >> 4) * 8 + j) * NFF + n16 * 16 + (lane & 15)]);
    } else if (i < PO_WE) {                // Wf2 [256][256]
        int t = i - PO_WF2;
        int j = t & 7, lane = (t >> 3) & 63, n16 = (t >> 9) & 15, ks = t >> 13;
        p[i] = bf16r(Wf2[(ks * 32 + (lane >> 4) * 8 + j) * NFF + n16 * 16 + (lane & 15)]);
    } else if (i < PO_WL1) {               // We [192][128]
        int t = i - PO_WE;
        int j = t & 7, lane = (t >> 3) & 63, n16 = (t >> 9) & 7, ks = t >> 12;
        p[i] = bf16r(We[(ks * 32 + (lane >> 4) * 8 + j) * CC + n16 * 16 + (lane & 15)]);
    } else if (i < PO_WL2) {               // Wl1 [128][256]
        int t = i - PO_WL1;
        int j = t & 7, lane = (t >> 3) & 63, n16 = (t >> 9) & 15, ks = t >> 13;
        p[i] = bf16r(Wl1[(ks * 32 + (lane >> 4) * 8 + j) * NFF + n16 * 16 + (lane & 15)]);
    } else if (i < PO_WL3) {               // Wl2 [256][128]
        int t = i - PO_WL2;
        int j = t & 7, lane = (t >> 3) & 63, n16 = (t >> 9) & 7, ks = t >> 12;
        p[i] = bf16r(Wl2[(ks * 32 + (lane >> 4) * 8 + j) * CC + n16 * 16 + (lane & 15)]);
    } else if (i < P_TOT) {                // Wl3 [128][128]
        int t = i - PO_WL3;
        int j = t & 7, lane = (t >> 3) & 63, n16 = (t >> 9) & 7, ks = t >> 12;
        p[i] = bf16r(Wl3[(ks * 32 + (lane >> 4) * 8 + j) * CC + n16 * 16 + (lane & 15)]);
    }
}

// ---- K0: zero ints/floats (float4 granularity) ----
__global__ void k0_zero(float* __restrict__ p, long n4) {
    long i = (long)blockIdx.x * blockDim.x + threadIdx.x;
    long stride = (long)gridDim.x * blockDim.x;
    float4 z = {0.f, 0.f, 0.f, 0.f};
    for (; i < n4; i += stride) ((float4*)p)[i] = z;
}

// ---- CSR build ----
__global__ void k_cnt(const int* __restrict__ eidx, int* __restrict__ cnt) {
    int e = blockIdx.x * 256 + threadIdx.x;
    if (e < NE) atomicAdd(&cnt[eidx[e]], 1);
}

// 3-phase scan (196 blocks of 256)
__global__ __launch_bounds__(256) void k_scan1(const int* __restrict__ cnt,
                                               int* __restrict__ offw,
                                               int* __restrict__ bsum) {
    __shared__ int sw_[4];
    int i = blockIdx.x * 256 + threadIdx.x;
    int lane = threadIdx.x & 63, wv = threadIdx.x >> 6;
    int v = (i < NN) ? cnt[i] : 0;
    int inc = v;
    #pragma unroll
    for (int d = 1; d < 64; d <<= 1) {
        int t = __shfl_up(inc, d, 64);
        if (lane >= d) inc += t;
    }
    if (lane == 63) sw_[wv] = inc;
    __syncthreads();
    int woff = 0;
    #pragma unroll
    for (int k = 0; k < 4; ++k) woff += (k < wv) ? sw_[k] : 0;
    if (i < NN) offw[i] = woff + inc - v;
    if (threadIdx.x == 255) bsum[blockIdx.x] = woff + inc;
}

__global__ __launch_bounds__(256) void k_scan2(int* __restrict__ bsum, int nb) {
    __shared__ int sw_[4];
    int t = threadIdx.x;
    int lane = t & 63, wv = t >> 6;
    int v = (t < nb) ? bsum[t] : 0;
    int inc = v;
    #pragma unroll
    for (int d = 1; d < 64; d <<= 1) {
        int s = __shfl_up(inc, d, 64);
        if (lane >= d) inc += s;
    }
    if (lane == 63) sw_[wv] = inc;
    __syncthreads();
    int woff = 0;
    #pragma unroll
    for (int k = 0; k < 4; ++k) woff += (k < wv) ? sw_[k] : 0;
    if (t < nb) bsum[t] = woff + inc - v;   // exclusive
}

__global__ void k_scan3(int* __restrict__ offw, const int* __restrict__ bsum,
                        int* __restrict__ rowptr) {
    int i = blockIdx.x * 256 + threadIdx.x;
    if (i < NN) {
        int v = offw[i] + bsum[blockIdx.x];
        offw[i] = v;
        rowptr[i] = v;
    }
    if (i == 0) rowptr[NN] = NE;
}

// dest[e] = slot of edge e in row-sorted order
__global__ void k_scatter(const int* __restrict__ eidx, int* __restrict__ offw,
                          int* __restrict__ dest) {
    int e = blockIdx.x * 256 + threadIdx.x;
    if (e < NE) dest[e] = atomicAdd(&offw[eidx[e]], 1);
}

// ---- K1: h[N,NF] = x[N,C] @ Wl1, MFMA, output bf16 ----
// 32 nodes/block, 4 waves; wave w owns cols [w*64, w*64+64)
__global__ __launch_bounds__(256) void k1_h(const float* __restrict__ x,
                                            const short* __restrict__ pWl1,
                                            short* __restrict__ h) {
    __shared__ char xS[32 * 256];   // [32][128] bf16, stride 256B, swizzled
    int n0 = blockIdx.x * 32;
    int tid = threadIdx.x;
    int lane = tid & 63, w = tid >> 6, q = lane >> 4, l15 = lane & 15;
    {
        int r = tid >> 3, seg = tid & 7;      // 16 cols per seg
        int rr = min(n0 + r, NN - 1);
        const float4* src = (const float4*)(x + (size_t)rr * CC + seg * 16);
        float4 f0 = src[0], f1 = src[1], f2 = src[2], f3 = src[3];
        bf16x8 c0 = {bf16r(f0.x), bf16r(f0.y), bf16r(f0.z), bf16r(f0.w),
                     bf16r(f1.x), bf16r(f1.y), bf16r(f1.z), bf16r(f1.w)};
        bf16x8 c1 = {bf16r(f2.x), bf16r(f2.y), bf16r(f2.z), bf16r(f2.w),
                     bf16r(f3.x), bf16r(f3.y), bf16r(f3.z), bf16r(f3.w)};
        int sw = (r & 7) << 4;
        *(bf16x8*)(xS + r * 256 + ((seg * 32) ^ sw)) = c0;
        *(bf16x8*)(xS + r * 256 + ((seg * 32 + 16) ^ sw)) = c1;
    }
    __syncthreads();

    f32x4 acc[2][4];
    #pragma unroll
    for (int mf = 0; mf < 2; ++mf)
        #pragma unroll
        for (int nf = 0; nf < 4; ++nf) acc[mf][nf] = f32x4{0.f, 0.f, 0.f, 0.f};

    #pragma unroll
    for (int ks = 0; ks < 4; ++ks) {
        bf16x8 a[2];
        #pragma unroll
        for (int mf = 0; mf < 2; ++mf) {
            int row = mf * 16 + l15;
            a[mf] = *(const bf16x8*)(xS + row * 256 + ((ks * 64 + q * 16) ^ ((row & 7) << 4)));
        }
        #pragma unroll
        for (int nf = 0; nf < 4; ++nf) {
            bf16x8 b = *(const bf16x8*)(pWl1 + PO_WL1 + (((ks * 16 + w * 4 + nf) * 64) + lane) * 8);
            #pragma unroll
            for (int mf = 0; mf < 2; ++mf)
                acc[mf][nf] = __builtin_amdgcn_mfma_f32_16x16x32_bf16(a[mf], b, acc[mf][nf], 0, 0, 0);
        }
    }
    #pragma unroll
    for (int nf = 0; nf < 4; ++nf) {
        int col = w * 64 + nf * 16 + l15;
        #pragma unroll
        for (int mf = 0; mf < 2; ++mf) {
            #pragma unroll
            for (int r = 0; r < 4; ++r) {
                int n = n0 + mf * 16 + q * 4 + r;
                if (n < NN) h[(size_t)n * NFF + col] = bf16r(acc[mf][nf][r]);
            }
        }
    }
}

// ---- K2a: MFMA filter-net + modulate -> msg written at SORTED slot ----
__global__ __launch_bounds__(256, 8) void k2a_msg(
        const float* __restrict__ ea, const int* __restrict__ eidx,
        const int* __restrict__ dest,
        const short* __restrict__ pW, const float* __restrict__ bf1v,
        const float* __restrict__ bf2v,
        const short* __restrict__ h, short* __restrict__ msg) {
    __shared__ char eaS[32 * 128];   // [32][64] bf16, swizzled
    __shared__ char t1S[32 * 512];   // t1 (swizzled); reused for staged h rows
    __shared__ int colS[32], destS[32];
    int e0 = blockIdx.x * 32;
    int tid = threadIdx.x;
    int lane = tid & 63, w = tid >> 6;
    int q = lane >> 4, l15 = lane & 15;

    if (tid < 32) {
        colS[tid] = eidx[NE + e0 + tid];
        destS[tid] = dest[e0 + tid];
    }

    {   // stage ea -> bf16 swizzled LDS
        int r = tid >> 3, cp = tid & 7;
        const float4* src = (const float4*)(ea + (size_t)(e0 + r) * ECH + cp * 8);
        float4 f0 = src[0], f1 = src[1];
        bf16x8 c0 = {bf16r(f0.x), bf16r(f0.y), bf16r(f0.z), bf16r(f0.w),
                     bf16r(f1.x), bf16r(f1.y), bf16r(f1.z), bf16r(f1.w)};
        int sw = (r & 7) << 4;
        *(bf16x8*)(eaS + r * 128 + ((cp * 16) ^ sw)) = c0;
    }
    __syncthreads();

    f32x4 acc[2][4];
    #pragma unroll
    for (int mf = 0; mf < 2; ++mf)
        #pragma unroll
        for (int nf = 0; nf < 4; ++nf) acc[mf][nf] = f32x4{0.f, 0.f, 0.f, 0.f};

    // phase 1: t1 = ssp(ea @ Wf1 + b1), K=64
    #pragma unroll
    for (int ks = 0; ks < 2; ++ks) {
        bf16x8 a[2];
        #pragma unroll
        for (int mf = 0; mf < 2; ++mf) {
            int row = mf * 16 + l15;
            a[mf] = *(const bf16x8*)(eaS + row * 128 + ((ks * 64 + q * 16) ^ ((row & 7) << 4)));
        }
        #pragma unroll
        for (int nf = 0; nf < 4; ++nf) {
            bf16x8 b = *(const bf16x8*)(pW + PO_WF1 + (((ks * 16 + w * 4 + nf) * 64) + lane) * 8);
            #pragma unroll
            for (int mf = 0; mf < 2; ++mf)
                acc[mf][nf] = __builtin_amdgcn_mfma_f32_16x16x32_bf16(a[mf], b, acc[mf][nf], 0, 0, 0);
        }
    }
    #pragma unroll
    for (int nf = 0; nf < 4; ++nf) {
        int col = w * 64 + nf * 16 + l15;
        float bias = bf1v[col];
        #pragma unroll
        for (int mf = 0; mf < 2; ++mf) {
            #pragma unroll
            for (int r = 0; r < 4; ++r) {
                int row = mf * 16 + q * 4 + r;
                *(short*)(t1S + row * 512 + ((col * 2) ^ ((row & 7) << 4))) =
                    bf16r(sspf(acc[mf][nf][r] + bias));
            }
        }
    }
    __syncthreads();

    #pragma unroll
    for (int mf = 0; mf < 2; ++mf)
        #pragma unroll
        for (int nf = 0; nf < 4; ++nf) acc[mf][nf] = f32x4{0.f, 0.f, 0.f, 0.f};

    // phase 2: Wf = t1 @ Wf2 + b2, K=256
    for (int ks = 0; ks < 8; ++ks) {
        bf16x8 a[2];
        #pragma unroll
        for (int mf = 0; mf < 2; ++mf) {
            int row = mf * 16 + l15;
            a[mf] = *(const bf16x8*)(t1S + row * 512 + ((ks * 64 + q * 16) ^ ((row & 7) << 4)));
        }
        #pragma unroll
        for (int nf = 0; nf < 4; ++nf) {
            bf16x8 b = *(const bf16x8*)(pW + PO_WF2 + (((ks * 16 + w * 4 + nf) * 64) + lane) * 8);
            #pragma unroll
            for (int mf = 0; mf < 2; ++mf)
                acc[mf][nf] = __builtin_amdgcn_mfma_f32_16x16x32_bf16(a[mf], b, acc[mf][nf], 0, 0, 0);
        }
    }
    __syncthreads();   // t1S reads done; reuse for h rows

    {   // stage h[colS[0..31]] into LDS
        int r = tid >> 3, ch = tid & 7;
        const short* hp = h + (size_t)colS[r] * NFF;
        int sw = (r & 7) << 4;
        #pragma unroll
        for (int i = 0; i < 4; ++i) {
            bf16x8 v = *(const bf16x8*)(hp + i * 64 + ch * 8);
            *(bf16x8*)(t1S + r * 512 + ((i * 128 + ch * 16) ^ sw)) = v;
        }
    }
    __syncthreads();

    // epilogue: msg[dest_e, col] = h[col_e, col] * Wf[e, col]
    #pragma unroll
    for (int nf = 0; nf < 4; ++nf) {
        int col = w * 64 + nf * 16 + l15;
        float bias = bf2v[col];
        #pragma unroll
        for (int mf = 0; mf < 2; ++mf) {
            #pragma unroll
            for (int r = 0; r < 4; ++r) {
                int eloc = mf * 16 + q * 4 + r;
                float wf = acc[mf][nf][r] + bias;
                float hv = bf2f(*(const short*)(t1S + eloc * 512 + ((col * 2) ^ ((eloc & 7) << 4))));
                msg[(size_t)destS[eloc] * NFF + col] = bf16r(hv * wf);
            }
        }
    }
}

// ---- K3 fused: contiguous CSR segment-sum + MFMA node GEMMs ----
// 32 nodes/block, 4 waves; wave w owns cols [w*32, w*32+32)
__global__ __launch_bounds__(256) void k3_node(
        const short* __restrict__ msg, const int* __restrict__ rowptr,
        const short* __restrict__ pW, const float* __restrict__ bl2,
        const float* __restrict__ bl3,
        const float* __restrict__ x, float* __restrict__ xo) {
    __shared__ char aggS[32 * 512];  // [32][256] bf16, swizzled
    __shared__ char t2S[32 * 256];   // [32][128] bf16, swizzled
    int n0 = blockIdx.x * 32;
    int tid = threadIdx.x;
    int lane = tid & 63, w = tid >> 6, q = lane >> 4, l15 = lane & 15;

    {   // segment-sum: 8 thr/node, 32 cols each, fp32; msg rows CONTIGUOUS
        int nd = tid >> 3, c0 = (tid & 7) * 32;
        int n = n0 + nd;
        int p0 = 0, p1 = 0;
        if (n < NN) { p0 = rowptr[n]; p1 = rowptr[n + 1]; }
        float a[32];
        #pragma unroll
        for (int i = 0; i < 32; ++i) a[i] = 0.f;
        for (int p = p0; p < p1; ++p) {
            const short* mrow = msg + (size_t)p * NFF + c0;
            #pragma unroll
            for (int j = 0; j < 4; ++j) {
                bf16x8 v = *(const bf16x8*)(mrow + j * 8);
                #pragma unroll
                for (int k = 0; k < 8; ++k) a[j * 8 + k] += bf2f(v[k]);
            }
        }
        int sw = (nd & 7) << 4;
        #pragma unroll
        for (int j = 0; j < 4; ++j) {
            bf16x8 v;
            #pragma unroll
            for (int k = 0; k < 8; ++k) v[k] = bf16r(a[j * 8 + k]);
            *(bf16x8*)(aggS + nd * 512 + (((c0 + j * 8) * 2) ^ sw)) = v;
        }
    }
    __syncthreads();

    // GEMM1: t2 = ssp(agg @ Wl2 + b2), [32,256]@[256,128]
    f32x4 acc[2][2];
    #pragma unroll
    for (int mf = 0; mf < 2; ++mf)
        #pragma unroll
        for (int nf = 0; nf < 2; ++nf) acc[mf][nf] = f32x4{0.f, 0.f, 0.f, 0.f};
    for (int ks = 0; ks < 8; ++ks) {
        bf16x8 a[2];
        #pragma unroll
        for (int mf = 0; mf < 2; ++mf) {
            int row = mf * 16 + l15;
            a[mf] = *(const bf16x8*)(aggS + row * 512 + ((ks * 64 + q * 16) ^ ((row & 7) << 4)));
        }
        #pragma unroll
        for (int nf = 0; nf < 2; ++nf) {
            bf16x8 b = *(const bf16x8*)(pW + PO_WL2 + (((ks * 8 + w * 2 + nf) * 64) + lane) * 8);
            #pragma unroll
            for (int mf = 0; mf < 2; ++mf)
                acc[mf][nf] = __builtin_amdgcn_mfma_f32_16x16x32_bf16(a[mf], b, acc[mf][nf], 0, 0, 0);
        }
    }
    #pragma unroll
    for (int nf = 0; nf < 2; ++nf) {
        int col = w * 32 + nf * 16 + l15;
        float bias = bl2[col];
        #pragma unroll
        for (int mf = 0; mf < 2; ++mf) {
            #pragma unroll
            for (int r = 0; r < 4; ++r) {
                int row = mf * 16 + q * 4 + r;
                *(short*)(t2S + row * 256 + ((col * 2) ^ ((row & 7) << 4))) =
                    bf16r(sspf(acc[mf][nf][r] + bias));
            }
        }
    }
    __syncthreads();

    // GEMM2: y = t2 @ Wl3 + b3, [32,128]@[128,128]
    f32x4 acc2[2][2];
    #pragma unroll
    for (int mf = 0; mf < 2; ++mf)
        #pragma unroll
        for (int nf = 0; nf < 2; ++nf) acc2[mf][nf] = f32x4{0.f, 0.f, 0.f, 0.f};
    #pragma unroll
    for (int ks = 0; ks < 4; ++ks) {
        bf16x8 a[2];
        #pragma unroll
        for (int mf = 0; mf < 2; ++mf) {
            int row = mf * 16 + l15;
            a[mf] = *(const bf16x8*)(t2S + row * 256 + ((ks * 64 + q * 16) ^ ((row & 7) << 4)));
        }
        #pragma unroll
        for (int nf = 0; nf < 2; ++nf) {
            bf16x8 b = *(const bf16x8*)(pW + PO_WL3 + (((ks * 8 + w * 2 + nf) * 64) + lane) * 8);
            #pragma unroll
            for (int mf = 0; mf < 2; ++mf)
                acc2[mf][nf] = __builtin_amdgcn_mfma_f32_16x16x32_bf16(a[mf], b, acc2[mf][nf], 0, 0, 0);
        }
    }
    // epilogue: relu + residual, fp32 store
    #pragma unroll
    for (int nf = 0; nf < 2; ++nf) {
        int col = w * 32 + nf * 16 + l15;
        float bias = bl3[col];
        #pragma unroll
        for (int mf = 0; mf < 2; ++mf) {
            #pragma unroll
            for (int r = 0; r < 4; ++r) {
                int n = n0 + mf * 16 + q * 4 + r;
                if (n < NN) {
                    size_t o = (size_t)n * CC + col;
                    xo[o] = fmaxf(acc2[mf][nf][r] + bias, 0.f) + x[o];
                }
            }
        }
    }
}

// ---- K4: MFMA e_out = tanh([ea | xo[row]+xo[col]] @ We + be) ----
__global__ __launch_bounds__(256) void k4_mfma(
        const float* __restrict__ ea, const int* __restrict__ eidx,
        const float* __restrict__ xo, const short* __restrict__ pW,
        const float* __restrict__ bev, float* __restrict__ eo) {
    __shared__ char aS[64 * 384];    // [64][192] bf16, swizzled
    int e0 = blockIdx.x * 64;
    int tid = threadIdx.x;
    int lane = tid & 63, w = tid >> 6;
    int q = lane >> 4, l15 = lane & 15;

    {   // stage ea (k 0..63)
        int r = tid >> 2, cp = tid & 3;
        const float4* src = (const float4*)(ea + (size_t)(e0 + r) * ECH + cp * 16);
        float4 f0 = src[0], f1 = src[1], f2 = src[2], f3 = src[3];
        bf16x8 c0 = {bf16r(f0.x), bf16r(f0.y), bf16r(f0.z), bf16r(f0.w),
                     bf16r(f1.x), bf16r(f1.y), bf16r(f1.z), bf16r(f1.w)};
        bf16x8 c1 = {bf16r(f2.x), bf16r(f2.y), bf16r(f2.z), bf16r(f2.w),
                     bf16r(f3.x), bf16r(f3.y), bf16r(f3.z), bf16r(f3.w)};
        int sw = (r & 7) << 4;
        *(bf16x8*)(aS + r * 384 + ((cp * 32) ^ sw)) = c0;
        *(bf16x8*)(aS + r * 384 + ((cp * 32 + 16) ^ sw)) = c1;
    }
    {   // stage xo[row]+xo[col] (k 64..191)
        int e = tid >> 2, p = tid & 3;
        int rr = eidx[e0 + e], cc = eidx[NE + e0 + e];
        const float4* xr = (const float4*)(xo + (size_t)rr * CC);
        const float4* xc = (const float4*)(xo + (size_t)cc * CC);
        int sw = (e & 7) << 4;
        #pragma unroll
        for (int it = 0; it < 8; ++it) {
            int fi = p + it * 4;
            float4 va = xr[fi], vb = xc[fi];
            bf16x4 hv = {bf16r(va.x + vb.x), bf16r(va.y + vb.y),
                         bf16r(va.z + vb.z), bf16r(va.w + vb.w)};
            int byte = (ECH + fi * 4) * 2;
            *(bf16x4*)(aS + e * 384 + (byte ^ sw)) = hv;
        }
    }
    __syncthreads();

    f32x4 acc[8];
    #pragma unroll
    for (int nf = 0; nf < 8; ++nf) acc[nf] = f32x4{0.f, 0.f, 0.f, 0.f};

    #pragma unroll
    for (int ks = 0; ks < 6; ++ks) {
        int row = w * 16 + l15;
        bf16x8 a = *(const bf16x8*)(aS + row * 384 + ((ks * 64 + q * 16) ^ ((row & 7) << 4)));
        #pragma unroll
        for (int nf = 0; nf < 8; ++nf) {
            bf16x8 b = *(const bf16x8*)(pW + PO_WE + (((ks * 8 + nf) * 64) + lane) * 8);
            acc[nf] = __builtin_amdgcn_mfma_f32_16x16x32_bf16(a, b, acc[nf], 0, 0, 0);
        }
    }
    #pragma unroll
    for (int nf = 0; nf < 8; ++nf) {
        int col = nf * 16 + l15;
        float bias = bev[col];
        #pragma unroll
        for (int r = 0; r < 4; ++r) {
            int e = e0 + w * 16 + q * 4 + r;
            eo[(size_t)e * CC + col] = ftanh(acc[nf][r] + bias);
        }
    }
}

extern "C" void kernel_launch(void* const* d_in, const int* in_sizes, int n_in,
                              void* d_out, int out_size, void* d_ws, size_t ws_size,
                              hipStream_t stream) {
    const float* x   = (const float*)d_in[0];
    const int*   ei  = (const int*)d_in[1];
    const float* ea  = (const float*)d_in[2];
    const float* Wf1 = (const float*)d_in[4];
    const float* bf1 = (const float*)d_in[5];
    const float* Wf2 = (const float*)d_in[6];
    const float* bf2 = (const float*)d_in[7];
    const float* Wl1 = (const float*)d_in[8];
    const float* Wl2 = (const float*)d_in[9];
    const float* bl2 = (const float*)d_in[10];
    const float* Wl3 = (const float*)d_in[11];
    const float* bl3 = (const float*)d_in[12];
    const float* We  = (const float*)d_in[13];
    const float* be  = (const float*)d_in[14];

    float* xo = (float*)d_out;                 // [N, C] final
    float* eo = xo + (size_t)NN * CC;          // [E, C] final

    // region reuse (sequential lifetimes):
    //   h   bf16 [N,256]  in xo region (dead before k3 writes xo)
    //   msg bf16 [E,256]  in eo region (dead before k4 writes eo)
    short* h   = (short*)xo;
    short* msg = (short*)eo;

    // ws: [packed weights 384KB][dest E][cnt N][offw N][rowptr N+1][bsum 256]
    short* pW    = (short*)d_ws;
    int* dest    = (int*)((char*)d_ws + 393216);
    int* cnt     = dest + NE;
    int* offw    = cnt + NN;
    int* rowptr  = offw + NN;
    int* bsum    = rowptr + NN + 1;

    const int NB = (NN + 255) / 256;   // 196 scan blocks

    kpack<<<P_TOT / 256, 256, 0, stream>>>(Wf1, Wf2, We, Wl1, Wl2, Wl3, pW);
    k0_zero<<<49, 256, 0, stream>>>((float*)cnt, NN / 4);
    k_cnt<<<(NE + 255) / 256, 256, 0, stream>>>(ei, cnt);
    k_scan1<<<NB, 256, 0, stream>>>(cnt, offw, bsum);
    k_scan2<<<1, 256, 0, stream>>>(bsum, NB);
    k_scan3<<<NB, 256, 0, stream>>>(offw, bsum, rowptr);
    k_scatter<<<(NE + 255) / 256, 256, 0, stream>>>(ei, offw, dest);
    k1_h<<<(NN + 31) / 32, 256, 0, stream>>>(x, pW, h);
    k2a_msg<<<NE / 32, 256, 0, stream>>>(ea, ei, dest, pW, bf1, bf2, h, msg);
    k3_node<<<(NN + 31) / 32, 256, 0, stream>>>(msg, rowptr, pW, bl2, bl3, x, xo);
    k4_mfma<<<NE / 64, 256, 0, stream>>>(ea, ei, xo, pW, be, eo);
}

// Round 8
// 582.137 us; speedup vs baseline: 2.6762x; 1.0328x over previous
//
#include <hip/hip_runtime.h>

#define NN  50000
#define NE  600000
#define CC  128
#define NFF 256
#define ECH 64
#define EIN 192   // ECH + CC

typedef __attribute__((ext_vector_type(8))) short bf16x8;
typedef __attribute__((ext_vector_type(4))) short bf16x4;
typedef __attribute__((ext_vector_type(4))) float f32x4;
typedef __attribute__((ext_vector_type(4))) unsigned u32x4;
typedef __attribute__((ext_vector_type(2))) unsigned u32x2;

// fast shifted-softplus: softplus(v)-ln2 via hw exp/log
__device__ __forceinline__ float sspf(float v) {
    float e = __expf(-fabsf(v));
    return fmaxf(v, 0.f) + __logf(1.f + e) - 0.693147180559945f;
}
// fast tanh via hw exp
__device__ __forceinline__ float ftanh(float v) {
    float e = __expf(-2.f * fabsf(v));
    float r = (1.f - e) / (1.f + e);
    return copysignf(r, v);
}
__device__ __forceinline__ short bf16r(float f) {
    unsigned u = __float_as_uint(f);
    u = (u + 0x7FFFu + ((u >> 16) & 1u)) >> 16;
    return (short)u;
}
// packed fp32x2 -> bf16x2 (RNE), single VALU op
__device__ __forceinline__ unsigned cvtpk(float lo, float hi) {
    unsigned r;
    asm("v_cvt_pk_bf16_f32 %0, %1, %2" : "=v"(r) : "v"(lo), "v"(hi));
    return r;
}
__device__ __forceinline__ float bfu_lo(unsigned u) { return __uint_as_float(u << 16); }
__device__ __forceinline__ float bfu_hi(unsigned u) { return __uint_as_float(u & 0xffff0000u); }

// ---- pack ALL weights to bf16 fragment-linear layout for mfma_16x16x32 B-op.
// Layout permutations: 256-col tensors (h, t1, msg/agg) live in fragment order
//   p = w*64 + l15*4 + nf   (orig col c = w*64 + nf*16 + l15)
// so consumers' k-dims are packed with orig_k(p) = (p>>6)*64+(p&3)*16+((p>>2)&15).
// 128-col t2 (k3-internal): p2 order, orig_k2(p) = (p>>5)*32+(p&1)*16+((p&31)>>1).
#define PO_WF1 0
#define PO_WF2 16384
#define PO_WE  81920
#define PO_WL1 106496
#define PO_WL2 139264
#define PO_WL3 172032
#define P_TOT  188416
__global__ void kpack(const float* __restrict__ Wf1, const float* __restrict__ Wf2,
                      const float* __restrict__ We,  const float* __restrict__ Wl1,
                      const float* __restrict__ Wl2, const float* __restrict__ Wl3,
                      short* __restrict__ p) {
    int i = blockIdx.x * 256 + threadIdx.x;
    if (i < PO_WF2) {                      // Wf1 [64][256]: k orig, n orig
        int t = i - PO_WF1;
        int j = t & 7, lane = (t >> 3) & 63, n16 = (t >> 9) & 15, ks = t >> 13;
        p[i] = bf16r(Wf1[(ks * 32 + (lane >> 4) * 8 + j) * NFF + n16 * 16 + (lane & 15)]);
    } else if (i < PO_WE) {                // Wf2 [256][256]: k in t1 p-order
        int t = i - PO_WF2;
        int j = t & 7, lane = (t >> 3) & 63, n16 = (t >> 9) & 15, ks = t >> 13;
        int kp = ks * 32 + (lane >> 4) * 8 + j;
        int k = (kp >> 6) * 64 + (kp & 3) * 16 + ((kp >> 2) & 15);
        p[i] = bf16r(Wf2[k * NFF + n16 * 16 + (lane & 15)]);
    } else if (i < PO_WL1) {               // We [192][128]: k orig, n orig
        int t = i - PO_WE;
        int j = t & 7, lane = (t >> 3) & 63, n16 = (t >> 9) & 7, ks = t >> 12;
        p[i] = bf16r(We[(ks * 32 + (lane >> 4) * 8 + j) * CC + n16 * 16 + (lane & 15)]);
    } else if (i < PO_WL2) {               // Wl1 [128][256]: k orig, n orig (h stored p-order at write)
        int t = i - PO_WL1;
        int j = t & 7, lane = (t >> 3) & 63, n16 = (t >> 9) & 15, ks = t >> 13;
        p[i] = bf16r(Wl1[(ks * 32 + (lane >> 4) * 8 + j) * NFF + n16 * 16 + (lane & 15)]);
    } else if (i < PO_WL3) {               // Wl2 [256][128]: k in agg p-order
        int t = i - PO_WL2;
        int j = t & 7, lane = (t >> 3) & 63, n16 = (t >> 9) & 7, ks = t >> 12;
        int kp = ks * 32 + (lane >> 4) * 8 + j;
        int k = (kp >> 6) * 64 + (kp & 3) * 16 + ((kp >> 2) & 15);
        p[i] = bf16r(Wl2[k * CC + n16 * 16 + (lane & 15)]);
    } else if (i < P_TOT) {                // Wl3 [128][128]: k in t2 p2-order
        int t = i - PO_WL3;
        int j = t & 7, lane = (t >> 3) & 63, n16 = (t >> 9) & 7, ks = t >> 12;
        int kp = ks * 32 + (lane >> 4) * 8 + j;
        int k = (kp >> 5) * 32 + (kp & 1) * 16 + ((kp & 31) >> 1);
        p[i] = bf16r(Wl3[k * CC + n16 * 16 + (lane & 15)]);
    }
}

// ---- K0: zero ----
__global__ void k0_zero(float* __restrict__ p, long n4) {
    long i = (long)blockIdx.x * blockDim.x + threadIdx.x;
    long stride = (long)gridDim.x * blockDim.x;
    float4 z = {0.f, 0.f, 0.f, 0.f};
    for (; i < n4; i += stride) ((float4*)p)[i] = z;
}

// ---- CSR build ----
__global__ void k_cnt(const int* __restrict__ eidx, int* __restrict__ cnt) {
    int e = blockIdx.x * 256 + threadIdx.x;
    if (e < NE) atomicAdd(&cnt[eidx[e]], 1);
}

__global__ __launch_bounds__(256) void k_scan1(const int* __restrict__ cnt,
                                               int* __restrict__ offw,
                                               int* __restrict__ bsum) {
    __shared__ int sw_[4];
    int i = blockIdx.x * 256 + threadIdx.x;
    int lane = threadIdx.x & 63, wv = threadIdx.x >> 6;
    int v = (i < NN) ? cnt[i] : 0;
    int inc = v;
    #pragma unroll
    for (int d = 1; d < 64; d <<= 1) {
        int t = __shfl_up(inc, d, 64);
        if (lane >= d) inc += t;
    }
    if (lane == 63) sw_[wv] = inc;
    __syncthreads();
    int woff = 0;
    #pragma unroll
    for (int k = 0; k < 4; ++k) woff += (k < wv) ? sw_[k] : 0;
    if (i < NN) offw[i] = woff + inc - v;
    if (threadIdx.x == 255) bsum[blockIdx.x] = woff + inc;
}

__global__ __launch_bounds__(256) void k_scan2(int* __restrict__ bsum, int nb) {
    __shared__ int sw_[4];
    int t = threadIdx.x;
    int lane = t & 63, wv = t >> 6;
    int v = (t < nb) ? bsum[t] : 0;
    int inc = v;
    #pragma unroll
    for (int d = 1; d < 64; d <<= 1) {
        int s = __shfl_up(inc, d, 64);
        if (lane >= d) inc += s;
    }
    if (lane == 63) sw_[wv] = inc;
    __syncthreads();
    int woff = 0;
    #pragma unroll
    for (int k = 0; k < 4; ++k) woff += (k < wv) ? sw_[k] : 0;
    if (t < nb) bsum[t] = woff + inc - v;
}

__global__ void k_scan3(int* __restrict__ offw, const int* __restrict__ bsum,
                        int* __restrict__ rowptr) {
    int i = blockIdx.x * 256 + threadIdx.x;
    if (i < NN) {
        int v = offw[i] + bsum[blockIdx.x];
        offw[i] = v;
        rowptr[i] = v;
    }
    if (i == 0) rowptr[NN] = NE;
}

__global__ void k_scatter(const int* __restrict__ eidx, int* __restrict__ offw,
                          int* __restrict__ dest) {
    int e = blockIdx.x * 256 + threadIdx.x;
    if (e < NE) dest[e] = atomicAdd(&offw[eidx[e]], 1);
}

// ---- K1: h[N,256] = x @ Wl1 (MFMA), h stored in p-order ----
__global__ __launch_bounds__(256) void k1_h(const float* __restrict__ x,
                                            const short* __restrict__ pW,
                                            short* __restrict__ h) {
    __shared__ char xS[32 * 256];   // [32][128] bf16, swizzled
    int n0 = blockIdx.x * 32;
    int tid = threadIdx.x;
    int lane = tid & 63, w = tid >> 6, q = lane >> 4, l15 = lane & 15;
    {
        int r = tid >> 3, seg = tid & 7;
        int rr = min(n0 + r, NN - 1);
        const float4* src = (const float4*)(x + (size_t)rr * CC + seg * 16);
        float4 f0 = src[0], f1 = src[1], f2 = src[2], f3 = src[3];
        u32x4 c0 = {cvtpk(f0.x, f0.y), cvtpk(f0.z, f0.w), cvtpk(f1.x, f1.y), cvtpk(f1.z, f1.w)};
        u32x4 c1 = {cvtpk(f2.x, f2.y), cvtpk(f2.z, f2.w), cvtpk(f3.x, f3.y), cvtpk(f3.z, f3.w)};
        int sw = (r & 7) << 4;
        *(u32x4*)(xS + r * 256 + ((seg * 32) ^ sw)) = c0;
        *(u32x4*)(xS + r * 256 + ((seg * 32 + 16) ^ sw)) = c1;
    }
    __syncthreads();

    f32x4 acc[2][4];
    #pragma unroll
    for (int mf = 0; mf < 2; ++mf)
        #pragma unroll
        for (int nf = 0; nf < 4; ++nf) acc[mf][nf] = f32x4{0.f, 0.f, 0.f, 0.f};

    #pragma unroll
    for (int ks = 0; ks < 4; ++ks) {
        bf16x8 a[2];
        #pragma unroll
        for (int mf = 0; mf < 2; ++mf) {
            int row = mf * 16 + l15;
            a[mf] = *(const bf16x8*)(xS + row * 256 + ((ks * 64 + q * 16) ^ ((row & 7) << 4)));
        }
        #pragma unroll
        for (int nf = 0; nf < 4; ++nf) {
            bf16x8 b = *(const bf16x8*)(pW + PO_WL1 + (((ks * 16 + w * 4 + nf) * 64) + lane) * 8);
            #pragma unroll
            for (int mf = 0; mf < 2; ++mf)
                acc[mf][nf] = __builtin_amdgcn_mfma_f32_16x16x32_bf16(a[mf], b, acc[mf][nf], 0, 0, 0);
        }
    }
    // store h in p-order: 8B per (mf,r)
    #pragma unroll
    for (int mf = 0; mf < 2; ++mf) {
        #pragma unroll
        for (int r = 0; r < 4; ++r) {
            int n = n0 + mf * 16 + q * 4 + r;
            if (n < NN) {
                u32x2 v = {cvtpk(acc[mf][0][r], acc[mf][1][r]),
                           cvtpk(acc[mf][2][r], acc[mf][3][r])};
                *(u32x2*)(h + (size_t)n * NFF + w * 64 + l15 * 4) = v;
            }
        }
    }
}

// ---- K2a: MFMA filter-net + modulate -> msg (p-order) at sorted slot ----
__global__ __launch_bounds__(256, 8) void k2a_msg(
        const float* __restrict__ ea, const int* __restrict__ eidx,
        const int* __restrict__ dest,
        const short* __restrict__ pW, const float* __restrict__ bf1v,
        const float* __restrict__ bf2v,
        const short* __restrict__ h, short* __restrict__ msg) {
    __shared__ char eaS[32 * 128];   // [32][64] bf16, swizzled
    __shared__ char t1S[32 * 512];   // t1 in p-order (swizzled); reused for h rows
    __shared__ int colS[32], destS[32];
    int e0 = blockIdx.x * 32;
    int tid = threadIdx.x;
    int lane = tid & 63, w = tid >> 6;
    int q = lane >> 4, l15 = lane & 15;

    if (tid < 32) {
        colS[tid] = eidx[NE + e0 + tid];
        destS[tid] = dest[e0 + tid];
    }

    {   // stage ea -> bf16 swizzled LDS
        int r = tid >> 3, cp = tid & 7;
        const float4* src = (const float4*)(ea + (size_t)(e0 + r) * ECH + cp * 8);
        float4 f0 = src[0], f1 = src[1];
        u32x4 c0 = {cvtpk(f0.x, f0.y), cvtpk(f0.z, f0.w), cvtpk(f1.x, f1.y), cvtpk(f1.z, f1.w)};
        int sw = (r & 7) << 4;
        *(u32x4*)(eaS + r * 128 + ((cp * 16) ^ sw)) = c0;
    }
    __syncthreads();

    f32x4 acc[2][4];
    #pragma unroll
    for (int mf = 0; mf < 2; ++mf)
        #pragma unroll
        for (int nf = 0; nf < 4; ++nf) acc[mf][nf] = f32x4{0.f, 0.f, 0.f, 0.f};

    // phase 1: t1 = ssp(ea @ Wf1 + b1), K=64
    #pragma unroll
    for (int ks = 0; ks < 2; ++ks) {
        bf16x8 a[2];
        #pragma unroll
        for (int mf = 0; mf < 2; ++mf) {
            int row = mf * 16 + l15;
            a[mf] = *(const bf16x8*)(eaS + row * 128 + ((ks * 64 + q * 16) ^ ((row & 7) << 4)));
        }
        #pragma unroll
        for (int nf = 0; nf < 4; ++nf) {
            bf16x8 b = *(const bf16x8*)(pW + PO_WF1 + (((ks * 16 + w * 4 + nf) * 64) + lane) * 8);
            #pragma unroll
            for (int mf = 0; mf < 2; ++mf)
                acc[mf][nf] = __builtin_amdgcn_mfma_f32_16x16x32_bf16(a[mf], b, acc[mf][nf], 0, 0, 0);
        }
    }
    // ssp + bias, write t1 in p-order: b64 per (mf,r)
    {
        float bia[4];
        #pragma unroll
        for (int nf = 0; nf < 4; ++nf) bia[nf] = bf1v[w * 64 + nf * 16 + l15];
        #pragma unroll
        for (int mf = 0; mf < 2; ++mf) {
            #pragma unroll
            for (int r = 0; r < 4; ++r) {
                int row = mf * 16 + q * 4 + r;
                u32x2 v = {cvtpk(sspf(acc[mf][0][r] + bia[0]), sspf(acc[mf][1][r] + bia[1])),
                           cvtpk(sspf(acc[mf][2][r] + bia[2]), sspf(acc[mf][3][r] + bia[3]))};
                *(u32x2*)(t1S + row * 512 + ((w * 128 + l15 * 8) ^ ((row & 7) << 4))) = v;
            }
        }
    }
    __syncthreads();

    #pragma unroll
    for (int mf = 0; mf < 2; ++mf)
        #pragma unroll
        for (int nf = 0; nf < 4; ++nf) acc[mf][nf] = f32x4{0.f, 0.f, 0.f, 0.f};

    // phase 2: Wf = t1 @ Wf2 + b2, K=256 (k in p-order, matches pWf2)
    for (int ks = 0; ks < 8; ++ks) {
        bf16x8 a[2];
        #pragma unroll
        for (int mf = 0; mf < 2; ++mf) {
            int row = mf * 16 + l15;
            a[mf] = *(const bf16x8*)(t1S + row * 512 + ((ks * 64 + q * 16) ^ ((row & 7) << 4)));
        }
        #pragma unroll
        for (int nf = 0; nf < 4; ++nf) {
            bf16x8 b = *(const bf16x8*)(pW + PO_WF2 + (((ks * 16 + w * 4 + nf) * 64) + lane) * 8);
            #pragma unroll
            for (int mf = 0; mf < 2; ++mf)
                acc[mf][nf] = __builtin_amdgcn_mfma_f32_16x16x32_bf16(a[mf], b, acc[mf][nf], 0, 0, 0);
        }
    }
    __syncthreads();   // t1S reads done; reuse for h rows

    {   // stage h[colS[0..31]] (p-order rows, straight copy) into LDS
        int r = tid >> 3, ch = tid & 7;
        const short* hp = h + (size_t)colS[r] * NFF;
        int sw = (r & 7) << 4;
        #pragma unroll
        for (int i = 0; i < 4; ++i) {
            bf16x8 v = *(const bf16x8*)(hp + i * 64 + ch * 8);
            *(bf16x8*)(t1S + r * 512 + ((i * 128 + ch * 16) ^ sw)) = v;
        }
    }
    __syncthreads();

    // epilogue: msg[dest_e, p] = h[col_e, p] * Wf[e, p]; b64 in, b64 out
    {
        float bia[4];
        #pragma unroll
        for (int nf = 0; nf < 4; ++nf) bia[nf] = bf2v[w * 64 + nf * 16 + l15];
        #pragma unroll
        for (int mf = 0; mf < 2; ++mf) {
            #pragma unroll
            for (int r = 0; r < 4; ++r) {
                int eloc = mf * 16 + q * 4 + r;
                u32x2 hv = *(const u32x2*)(t1S + eloc * 512 + ((w * 128 + l15 * 8) ^ ((eloc & 7) << 4)));
                float m0 = bfu_lo(hv[0]) * (acc[mf][0][r] + bia[0]);
                float m1 = bfu_hi(hv[0]) * (acc[mf][1][r] + bia[1]);
                float m2 = bfu_lo(hv[1]) * (acc[mf][2][r] + bia[2]);
                float m3 = bfu_hi(hv[1]) * (acc[mf][3][r] + bia[3]);
                u32x2 out = {cvtpk(m0, m1), cvtpk(m2, m3)};
                *(u32x2*)(msg + (size_t)destS[eloc] * NFF + w * 64 + l15 * 4) = out;
            }
        }
    }
}

// ---- K3 fused: contiguous CSR segment-sum (p-order) + MFMA node GEMMs ----
__global__ __launch_bounds__(256) void k3_node(
        const short* __restrict__ msg, const int* __restrict__ rowptr,
        const short* __restrict__ pW, const float* __restrict__ bl2,
        const float* __restrict__ bl3,
        const float* __restrict__ x, float* __restrict__ xo) {
    __shared__ char aggS[32 * 512];  // [32][256] bf16 p-order, swizzled
    __shared__ char t2S[32 * 256];   // [32][128] bf16 p2-order, swizzled
    int n0 = blockIdx.x * 32;
    int tid = threadIdx.x;
    int lane = tid & 63, w = tid >> 6, q = lane >> 4, l15 = lane & 15;

    {   // segment-sum: 8 thr/node, 32 cols each; msg rows contiguous
        int nd = tid >> 3, c0 = (tid & 7) * 32;
        int n = n0 + nd;
        int p0 = 0, p1 = 0;
        if (n < NN) { p0 = rowptr[n]; p1 = rowptr[n + 1]; }
        float a[32];
        #pragma unroll
        for (int i = 0; i < 32; ++i) a[i] = 0.f;
        for (int p = p0; p < p1; ++p) {
            const short* mrow = msg + (size_t)p * NFF + c0;
            #pragma unroll
            for (int j = 0; j < 4; ++j) {
                u32x4 v = *(const u32x4*)(mrow + j * 8);
                #pragma unroll
                for (int k = 0; k < 4; ++k) {
                    a[j * 8 + 2 * k]     += bfu_lo(v[k]);
                    a[j * 8 + 2 * k + 1] += bfu_hi(v[k]);
                }
            }
        }
        int sw = (nd & 7) << 4;
        #pragma unroll
        for (int j = 0; j < 4; ++j) {
            u32x4 v = {cvtpk(a[j * 8 + 0], a[j * 8 + 1]), cvtpk(a[j * 8 + 2], a[j * 8 + 3]),
                       cvtpk(a[j * 8 + 4], a[j * 8 + 5]), cvtpk(a[j * 8 + 6], a[j * 8 + 7])};
            *(u32x4*)(aggS + nd * 512 + (((c0 + j * 8) * 2) ^ sw)) = v;
        }
    }
    __syncthreads();

    // GEMM1: t2 = ssp(agg @ Wl2 + b2), k in p-order (pWl2 matches)
    f32x4 acc[2][2];
    #pragma unroll
    for (int mf = 0; mf < 2; ++mf)
        #pragma unroll
        for (int nf = 0; nf < 2; ++nf) acc[mf][nf] = f32x4{0.f, 0.f, 0.f, 0.f};
    for (int ks = 0; ks < 8; ++ks) {
        bf16x8 a[2];
        #pragma unroll
        for (int mf = 0; mf < 2; ++mf) {
            int row = mf * 16 + l15;
            a[mf] = *(const bf16x8*)(aggS + row * 512 + ((ks * 64 + q * 16) ^ ((row & 7) << 4)));
        }
        #pragma unroll
        for (int nf = 0; nf < 2; ++nf) {
            bf16x8 b = *(const bf16x8*)(pW + PO_WL2 + (((ks * 8 + w * 2 + nf) * 64) + lane) * 8);
            #pragma unroll
            for (int mf = 0; mf < 2; ++mf)
                acc[mf][nf] = __builtin_amdgcn_mfma_f32_16x16x32_bf16(a[mf], b, acc[mf][nf], 0, 0, 0);
        }
    }
    {   // t2 in p2-order: b32 per (mf,r)
        float bia[2];
        #pragma unroll
        for (int nf = 0; nf < 2; ++nf) bia[nf] = bl2[w * 32 + nf * 16 + l15];
        #pragma unroll
        for (int mf = 0; mf < 2; ++mf) {
            #pragma unroll
            for (int r = 0; r < 4; ++r) {
                int row = mf * 16 + q * 4 + r;
                unsigned u = cvtpk(sspf(acc[mf][0][r] + bia[0]), sspf(acc[mf][1][r] + bia[1]));
                *(unsigned*)(t2S + row * 256 + ((w * 64 + l15 * 4) ^ ((row & 7) << 4))) = u;
            }
        }
    }
    __syncthreads();

    // GEMM2: y = t2 @ Wl3 + b3, k in p2-order (pWl3 matches)
    f32x4 acc2[2][2];
    #pragma unroll
    for (int mf = 0; mf < 2; ++mf)
        #pragma unroll
        for (int nf = 0; nf < 2; ++nf) acc2[mf][nf] = f32x4{0.f, 0.f, 0.f, 0.f};
    #pragma unroll
    for (int ks = 0; ks < 4; ++ks) {
        bf16x8 a[2];
        #pragma unroll
        for (int mf = 0; mf < 2; ++mf) {
            int row = mf * 16 + l15;
            a[mf] = *(const bf16x8*)(t2S + row * 256 + ((ks * 64 + q * 16) ^ ((row & 7) << 4)));
        }
        #pragma unroll
        for (int nf = 0; nf < 2; ++nf) {
            bf16x8 b = *(const bf16x8*)(pW + PO_WL3 + (((ks * 8 + w * 2 + nf) * 64) + lane) * 8);
            #pragma unroll
            for (int mf = 0; mf < 2; ++mf)
                acc2[mf][nf] = __builtin_amdgcn_mfma_f32_16x16x32_bf16(a[mf], b, acc2[mf][nf], 0, 0, 0);
        }
    }
    #pragma unroll
    for (int nf = 0; nf < 2; ++nf) {
        int col = w * 32 + nf * 16 + l15;
        float bias = bl3[col];
        #pragma unroll
        for (int mf = 0; mf < 2; ++mf) {
            #pragma unroll
            for (int r = 0; r < 4; ++r) {
                int n = n0 + mf * 16 + q * 4 + r;
                if (n < NN) {
                    size_t o = (size_t)n * CC + col;
                    xo[o] = fmaxf(acc2[mf][nf][r] + bias, 0.f) + x[o];
                }
            }
        }
    }
}

// ---- K4: MFMA e_out = tanh([ea | xo[row]+xo[col]] @ We + be) ----
__global__ __launch_bounds__(256) void k4_mfma(
        const float* __restrict__ ea, const int* __restrict__ eidx,
        const float* __restrict__ xo, const short* __restrict__ pW,
        const float* __restrict__ bev, float* __restrict__ eo) {
    __shared__ char aS[64 * 384];    // [64][192] bf16, swizzled
    int e0 = blockIdx.x * 64;
    int tid = threadIdx.x;
    int lane = tid & 63, w = tid >> 6;
    int q = lane >> 4, l15 = lane & 15;

    {   // stage ea (k 0..63)
        int r = tid >> 2, cp = tid & 3;
        const float4* src = (const float4*)(ea + (size_t)(e0 + r) * ECH + cp * 16);
        float4 f0 = src[0], f1 = src[1], f2 = src[2], f3 = src[3];
        u32x4 c0 = {cvtpk(f0.x, f0.y), cvtpk(f0.z, f0.w), cvtpk(f1.x, f1.y), cvtpk(f1.z, f1.w)};
        u32x4 c1 = {cvtpk(f2.x, f2.y), cvtpk(f2.z, f2.w), cvtpk(f3.x, f3.y), cvtpk(f3.z, f3.w)};
        int sw = (r & 7) << 4;
        *(u32x4*)(aS + r * 384 + ((cp * 32) ^ sw)) = c0;
        *(u32x4*)(aS + r * 384 + ((cp * 32 + 16) ^ sw)) = c1;
    }
    {   // stage xo[row]+xo[col] (k 64..191)
        int e = tid >> 2, p = tid & 3;
        int rr = eidx[e0 + e], cc = eidx[NE + e0 + e];
        const float4* xr = (const float4*)(xo + (size_t)rr * CC);
        const float4* xc = (const float4*)(xo + (size_t)cc * CC);
        int sw = (e & 7) << 4;
        #pragma unroll
        for (int it = 0; it < 8; ++it) {
            int fi = p + it * 4;
            float4 va = xr[fi], vb = xc[fi];
            u32x2 hv = {cvtpk(va.x + vb.x, va.y + vb.y), cvtpk(va.z + vb.z, va.w + vb.w)};
            int byte = (ECH + fi * 4) * 2;
            *(u32x2*)(aS + e * 384 + (byte ^ sw)) = hv;
        }
    }
    __syncthreads();

    f32x4 acc[8];
    #pragma unroll
    for (int nf = 0; nf < 8; ++nf) acc[nf] = f32x4{0.f, 0.f, 0.f, 0.f};

    #pragma unroll
    for (int ks = 0; ks < 6; ++ks) {
        int row = w * 16 + l15;
        bf16x8 a = *(const bf16x8*)(aS + row * 384 + ((ks * 64 + q * 16) ^ ((row & 7) << 4)));
        #pragma unroll
        for (int nf = 0; nf < 8; ++nf) {
            bf16x8 b = *(const bf16x8*)(pW + PO_WE + (((ks * 8 + nf) * 64) + lane) * 8);
            acc[nf] = __builtin_amdgcn_mfma_f32_16x16x32_bf16(a, b, acc[nf], 0, 0, 0);
        }
    }
    #pragma unroll
    for (int nf = 0; nf < 8; ++nf) {
        int col = nf * 16 + l15;
        float bias = bev[col];
        #pragma unroll
        for (int r = 0; r < 4; ++r) {
            int e = e0 + w * 16 + q * 4 + r;
            eo[(size_t)e * CC + col] = ftanh(acc[nf][r] + bias);
        }
    }
}

extern "C" void kernel_launch(void* const* d_in, const int* in_sizes, int n_in,
                              void* d_out, int out_size, void* d_ws, size_t ws_size,
                              hipStream_t stream) {
    const float* x   = (const float*)d_in[0];
    const int*   ei  = (const int*)d_in[1];
    const float* ea  = (const float*)d_in[2];
    const float* Wf1 = (const float*)d_in[4];
    const float* bf1 = (const float*)d_in[5];
    const float* Wf2 = (const float*)d_in[6];
    const float* bf2 = (const float*)d_in[7];
    const float* Wl1 = (const float*)d_in[8];
    const float* Wl2 = (const float*)d_in[9];
    const float* bl2 = (const float*)d_in[10];
    const float* Wl3 = (const float*)d_in[11];
    const float* bl3 = (const float*)d_in[12];
    const float* We  = (const float*)d_in[13];
    const float* be  = (const float*)d_in[14];

    float* xo = (float*)d_out;                 // [N, C] final
    float* eo = xo + (size_t)NN * CC;          // [E, C] final

    // region reuse (sequential lifetimes):
    short* h   = (short*)xo;   // bf16 [N,256] p-order, dead before k3 writes xo
    short* msg = (short*)eo;   // bf16 [E,256] p-order, dead before k4 writes eo

    // ws: [packed weights 384KB][dest E][cnt N][offw N][rowptr N+1][bsum 256]
    short* pW    = (short*)d_ws;
    int* dest    = (int*)((char*)d_ws + 393216);
    int* cnt     = dest + NE;
    int* offw    = cnt + NN;
    int* rowptr  = offw + NN;
    int* bsum    = rowptr + NN + 1;

    const int NB = (NN + 255) / 256;

    kpack<<<P_TOT / 256, 256, 0, stream>>>(Wf1, Wf2, We, Wl1, Wl2, Wl3, pW);
    k0_zero<<<49, 256, 0, stream>>>((float*)cnt, NN / 4);
    k_cnt<<<(NE + 255) / 256, 256, 0, stream>>>(ei, cnt);
    k_scan1<<<NB, 256, 0, stream>>>(cnt, offw, bsum);
    k_scan2<<<1, 256, 0, stream>>>(bsum, NB);
    k_scan3<<<NB, 256, 0, stream>>>(offw, bsum, rowptr);
    k_scatter<<<(NE + 255) / 256, 256, 0, stream>>>(ei, offw, dest);
    k1_h<<<(NN + 31) / 32, 256, 0, stream>>>(x, pW, h);
    k2a_msg<<<NE / 32, 256, 0, stream>>>(ea, ei, dest, pW, bf1, bf2, h, msg);
    k3_node<<<(NN + 31) / 32, 256, 0, stream>>>(msg, rowptr, pW, bl2, bl3, x, xo);
    k4_mfma<<<NE / 64, 256, 0, stream>>>(ea, ei, xo, pW, be, eo);
}

// Round 9
// 548.120 us; speedup vs baseline: 2.8423x; 1.0621x over previous
//
#include <hip/hip_runtime.h>

#define NN  50000
#define NE  600000
#define CC  128
#define NFF 256
#define ECH 64
#define EIN 192   // ECH + CC

typedef __attribute__((ext_vector_type(8))) short bf16x8;
typedef __attribute__((ext_vector_type(4))) short bf16x4;
typedef __attribute__((ext_vector_type(4))) float f32x4;
typedef __attribute__((ext_vector_type(4))) unsigned u32x4;
typedef __attribute__((ext_vector_type(2))) unsigned u32x2;

// fast shifted-softplus: softplus(v)-ln2 via hw exp/log
__device__ __forceinline__ float sspf(float v) {
    float e = __expf(-fabsf(v));
    return fmaxf(v, 0.f) + __logf(1.f + e) - 0.693147180559945f;
}
// fast tanh via hw exp
__device__ __forceinline__ float ftanh(float v) {
    float e = __expf(-2.f * fabsf(v));
    float r = (1.f - e) / (1.f + e);
    return copysignf(r, v);
}
__device__ __forceinline__ short bf16r(float f) {
    unsigned u = __float_as_uint(f);
    u = (u + 0x7FFFu + ((u >> 16) & 1u)) >> 16;
    return (short)u;
}
// packed fp32x2 -> bf16x2 (RNE), single VALU op
__device__ __forceinline__ unsigned cvtpk(float lo, float hi) {
    unsigned r;
    asm("v_cvt_pk_bf16_f32 %0, %1, %2" : "=v"(r) : "v"(lo), "v"(hi));
    return r;
}
__device__ __forceinline__ float bfu_lo(unsigned u) { return __uint_as_float(u << 16); }
__device__ __forceinline__ float bfu_hi(unsigned u) { return __uint_as_float(u & 0xffff0000u); }

// ---- pack ALL weights to bf16 fragment-linear layout for mfma_16x16x32 B-op.
// 256-col tensors (h, t1, msg/agg) live in fragment order p = w*64 + l15*4 + nf;
// consumers' k-dims packed with orig_k(p) = (p>>6)*64+(p&3)*16+((p>>2)&15).
// 128-col t2 (k3-internal): p2 order, orig_k2(p) = (p>>5)*32+(p&1)*16+((p&31)>>1).
#define PO_WF1 0
#define PO_WF2 16384
#define PO_WE  81920
#define PO_WL1 106496
#define PO_WL2 139264
#define PO_WL3 172032
#define P_TOT  188416
__global__ void kpack(const float* __restrict__ Wf1, const float* __restrict__ Wf2,
                      const float* __restrict__ We,  const float* __restrict__ Wl1,
                      const float* __restrict__ Wl2, const float* __restrict__ Wl3,
                      short* __restrict__ p) {
    int i = blockIdx.x * 256 + threadIdx.x;
    if (i < PO_WF2) {                      // Wf1 [64][256]: k orig, n orig
        int t = i - PO_WF1;
        int j = t & 7, lane = (t >> 3) & 63, n16 = (t >> 9) & 15, ks = t >> 13;
        p[i] = bf16r(Wf1[(ks * 32 + (lane >> 4) * 8 + j) * NFF + n16 * 16 + (lane & 15)]);
    } else if (i < PO_WE) {                // Wf2 [256][256]: k in t1 p-order
        int t = i - PO_WF2;
        int j = t & 7, lane = (t >> 3) & 63, n16 = (t >> 9) & 15, ks = t >> 13;
        int kp = ks * 32 + (lane >> 4) * 8 + j;
        int k = (kp >> 6) * 64 + (kp & 3) * 16 + ((kp >> 2) & 15);
        p[i] = bf16r(Wf2[k * NFF + n16 * 16 + (lane & 15)]);
    } else if (i < PO_WL1) {               // We [192][128]: k orig, n orig
        int t = i - PO_WE;
        int j = t & 7, lane = (t >> 3) & 63, n16 = (t >> 9) & 7, ks = t >> 12;
        p[i] = bf16r(We[(ks * 32 + (lane >> 4) * 8 + j) * CC + n16 * 16 + (lane & 15)]);
    } else if (i < PO_WL2) {               // Wl1 [128][256]: k orig, n orig
        int t = i - PO_WL1;
        int j = t & 7, lane = (t >> 3) & 63, n16 = (t >> 9) & 15, ks = t >> 13;
        p[i] = bf16r(Wl1[(ks * 32 + (lane >> 4) * 8 + j) * NFF + n16 * 16 + (lane & 15)]);
    } else if (i < PO_WL3) {               // Wl2 [256][128]: k in agg p-order
        int t = i - PO_WL2;
        int j = t & 7, lane = (t >> 3) & 63, n16 = (t >> 9) & 7, ks = t >> 12;
        int kp = ks * 32 + (lane >> 4) * 8 + j;
        int k = (kp >> 6) * 64 + (kp & 3) * 16 + ((kp >> 2) & 15);
        p[i] = bf16r(Wl2[k * CC + n16 * 16 + (lane & 15)]);
    } else if (i < P_TOT) {                // Wl3 [128][128]: k in t2 p2-order
        int t = i - PO_WL3;
        int j = t & 7, lane = (t >> 3) & 63, n16 = (t >> 9) & 7, ks = t >> 12;
        int kp = ks * 32 + (lane >> 4) * 8 + j;
        int k = (kp >> 5) * 32 + (kp & 1) * 16 + ((kp & 31) >> 1);
        p[i] = bf16r(Wl3[k * CC + n16 * 16 + (lane & 15)]);
    }
}

// ---- K0: zero ----
__global__ void k0_zero(float* __restrict__ p, long n4) {
    long i = (long)blockIdx.x * blockDim.x + threadIdx.x;
    long stride = (long)gridDim.x * blockDim.x;
    float4 z = {0.f, 0.f, 0.f, 0.f};
    for (; i < n4; i += stride) ((float4*)p)[i] = z;
}

// ---- CSR build ----
__global__ void k_cnt(const int* __restrict__ eidx, int* __restrict__ cnt) {
    int e = blockIdx.x * 256 + threadIdx.x;
    if (e < NE) atomicAdd(&cnt[eidx[e]], 1);
}

__global__ __launch_bounds__(256) void k_scan1(const int* __restrict__ cnt,
                                               int* __restrict__ offw,
                                               int* __restrict__ bsum) {
    __shared__ int sw_[4];
    int i = blockIdx.x * 256 + threadIdx.x;
    int lane = threadIdx.x & 63, wv = threadIdx.x >> 6;
    int v = (i < NN) ? cnt[i] : 0;
    int inc = v;
    #pragma unroll
    for (int d = 1; d < 64; d <<= 1) {
        int t = __shfl_up(inc, d, 64);
        if (lane >= d) inc += t;
    }
    if (lane == 63) sw_[wv] = inc;
    __syncthreads();
    int woff = 0;
    #pragma unroll
    for (int k = 0; k < 4; ++k) woff += (k < wv) ? sw_[k] : 0;
    if (i < NN) offw[i] = woff + inc - v;
    if (threadIdx.x == 255) bsum[blockIdx.x] = woff + inc;
}

__global__ __launch_bounds__(256) void k_scan2(int* __restrict__ bsum, int nb) {
    __shared__ int sw_[4];
    int t = threadIdx.x;
    int lane = t & 63, wv = t >> 6;
    int v = (t < nb) ? bsum[t] : 0;
    int inc = v;
    #pragma unroll
    for (int d = 1; d < 64; d <<= 1) {
        int s = __shfl_up(inc, d, 64);
        if (lane >= d) inc += s;
    }
    if (lane == 63) sw_[wv] = inc;
    __syncthreads();
    int woff = 0;
    #pragma unroll
    for (int k = 0; k < 4; ++k) woff += (k < wv) ? sw_[k] : 0;
    if (t < nb) bsum[t] = woff + inc - v;
}

__global__ void k_scan3(int* __restrict__ offw, const int* __restrict__ bsum,
                        int* __restrict__ rowptr) {
    int i = blockIdx.x * 256 + threadIdx.x;
    if (i < NN) {
        int v = offw[i] + bsum[blockIdx.x];
        offw[i] = v;
        rowptr[i] = v;
    }
    if (i == 0) rowptr[NN] = NE;
}

__global__ void k_scatter(const int* __restrict__ eidx, int* __restrict__ offw,
                          int* __restrict__ dest) {
    int e = blockIdx.x * 256 + threadIdx.x;
    if (e < NE) dest[e] = atomicAdd(&offw[eidx[e]], 1);
}

// ---- K1: h[N,256] = x @ Wl1 (MFMA), h stored in p-order ----
__global__ __launch_bounds__(256) void k1_h(const float* __restrict__ x,
                                            const short* __restrict__ pW,
                                            short* __restrict__ h) {
    __shared__ char xS[32 * 256];   // [32][128] bf16, swizzled
    int n0 = blockIdx.x * 32;
    int tid = threadIdx.x;
    int lane = tid & 63, w = tid >> 6, q = lane >> 4, l15 = lane & 15;
    {
        int r = tid >> 3, seg = tid & 7;
        int rr = min(n0 + r, NN - 1);
        const float4* src = (const float4*)(x + (size_t)rr * CC + seg * 16);
        float4 f0 = src[0], f1 = src[1], f2 = src[2], f3 = src[3];
        u32x4 c0 = {cvtpk(f0.x, f0.y), cvtpk(f0.z, f0.w), cvtpk(f1.x, f1.y), cvtpk(f1.z, f1.w)};
        u32x4 c1 = {cvtpk(f2.x, f2.y), cvtpk(f2.z, f2.w), cvtpk(f3.x, f3.y), cvtpk(f3.z, f3.w)};
        int sw = (r & 7) << 4;
        *(u32x4*)(xS + r * 256 + ((seg * 32) ^ sw)) = c0;
        *(u32x4*)(xS + r * 256 + ((seg * 32 + 16) ^ sw)) = c1;
    }
    __syncthreads();

    f32x4 acc[2][4];
    #pragma unroll
    for (int mf = 0; mf < 2; ++mf)
        #pragma unroll
        for (int nf = 0; nf < 4; ++nf) acc[mf][nf] = f32x4{0.f, 0.f, 0.f, 0.f};

    #pragma unroll
    for (int ks = 0; ks < 4; ++ks) {
        bf16x8 a[2];
        #pragma unroll
        for (int mf = 0; mf < 2; ++mf) {
            int row = mf * 16 + l15;
            a[mf] = *(const bf16x8*)(xS + row * 256 + ((ks * 64 + q * 16) ^ ((row & 7) << 4)));
        }
        #pragma unroll
        for (int nf = 0; nf < 4; ++nf) {
            bf16x8 b = *(const bf16x8*)(pW + PO_WL1 + (((ks * 16 + w * 4 + nf) * 64) + lane) * 8);
            #pragma unroll
            for (int mf = 0; mf < 2; ++mf)
                acc[mf][nf] = __builtin_amdgcn_mfma_f32_16x16x32_bf16(a[mf], b, acc[mf][nf], 0, 0, 0);
        }
    }
    #pragma unroll
    for (int mf = 0; mf < 2; ++mf) {
        #pragma unroll
        for (int r = 0; r < 4; ++r) {
            int n = n0 + mf * 16 + q * 4 + r;
            if (n < NN) {
                u32x2 v = {cvtpk(acc[mf][0][r], acc[mf][1][r]),
                           cvtpk(acc[mf][2][r], acc[mf][3][r])};
                *(u32x2*)(h + (size_t)n * NFF + w * 64 + l15 * 4) = v;
            }
        }
    }
}

// ---- K2a: MFMA filter-net + modulate -> msg (p-order) at sorted slot ----
// 64 edges/block, 4 waves; wave w owns cols [w*64, w*64+64); acc[4][4].
// eaS aliases t1S (disjoint lifetimes, extra barrier after phase 1).
__global__ __launch_bounds__(256, 4) void k2a_msg(
        const float* __restrict__ ea, const int* __restrict__ eidx,
        const int* __restrict__ dest,
        const short* __restrict__ pW, const float* __restrict__ bf1v,
        const float* __restrict__ bf2v,
        const short* __restrict__ h, short* __restrict__ msg) {
    __shared__ char t1S[64 * 512];   // phase1: ea [64][64]bf16 in first 8KB;
                                     // then t1 [64][256]bf16 p-order; then h rows
    __shared__ int colS[64], destS[64];
    char* eaS = t1S;
    int e0 = blockIdx.x * 64;
    int tid = threadIdx.x;
    int lane = tid & 63, w = tid >> 6;
    int q = lane >> 4, l15 = lane & 15;

    if (tid < 64) {
        colS[tid] = eidx[NE + e0 + tid];
        destS[tid] = dest[e0 + tid];
    }

    {   // stage ea -> bf16 swizzled LDS: 4 threads/row, 16 cols each
        int r = tid >> 2, cp = tid & 3;
        const float4* src = (const float4*)(ea + (size_t)(e0 + r) * ECH + cp * 16);
        float4 f0 = src[0], f1 = src[1], f2 = src[2], f3 = src[3];
        u32x4 c0 = {cvtpk(f0.x, f0.y), cvtpk(f0.z, f0.w), cvtpk(f1.x, f1.y), cvtpk(f1.z, f1.w)};
        u32x4 c1 = {cvtpk(f2.x, f2.y), cvtpk(f2.z, f2.w), cvtpk(f3.x, f3.y), cvtpk(f3.z, f3.w)};
        int sw = (r & 7) << 4;
        *(u32x4*)(eaS + r * 128 + ((cp * 32) ^ sw)) = c0;
        *(u32x4*)(eaS + r * 128 + ((cp * 32 + 16) ^ sw)) = c1;
    }
    __syncthreads();

    f32x4 acc[4][4];
    #pragma unroll
    for (int mf = 0; mf < 4; ++mf)
        #pragma unroll
        for (int nf = 0; nf < 4; ++nf) acc[mf][nf] = f32x4{0.f, 0.f, 0.f, 0.f};

    // phase 1: t1 = ssp(ea @ Wf1 + b1), K=64, M=64
    #pragma unroll
    for (int ks = 0; ks < 2; ++ks) {
        bf16x8 a[4];
        #pragma unroll
        for (int mf = 0; mf < 4; ++mf) {
            int row = mf * 16 + l15;
            a[mf] = *(const bf16x8*)(eaS + row * 128 + ((ks * 64 + q * 16) ^ ((row & 7) << 4)));
        }
        #pragma unroll
        for (int nf = 0; nf < 4; ++nf) {
            bf16x8 b = *(const bf16x8*)(pW + PO_WF1 + (((ks * 16 + w * 4 + nf) * 64) + lane) * 8);
            #pragma unroll
            for (int mf = 0; mf < 4; ++mf)
                acc[mf][nf] = __builtin_amdgcn_mfma_f32_16x16x32_bf16(a[mf], b, acc[mf][nf], 0, 0, 0);
        }
    }
    __syncthreads();   // eaS reads done before t1 overwrites the region

    // ssp + bias, write t1 in p-order: b64 per (mf,r)
    {
        float bia[4];
        #pragma unroll
        for (int nf = 0; nf < 4; ++nf) bia[nf] = bf1v[w * 64 + nf * 16 + l15];
        #pragma unroll
        for (int mf = 0; mf < 4; ++mf) {
            #pragma unroll
            for (int r = 0; r < 4; ++r) {
                int row = mf * 16 + q * 4 + r;
                u32x2 v = {cvtpk(sspf(acc[mf][0][r] + bia[0]), sspf(acc[mf][1][r] + bia[1])),
                           cvtpk(sspf(acc[mf][2][r] + bia[2]), sspf(acc[mf][3][r] + bia[3]))};
                *(u32x2*)(t1S + row * 512 + ((w * 128 + l15 * 8) ^ ((row & 7) << 4))) = v;
            }
        }
    }
    __syncthreads();

    #pragma unroll
    for (int mf = 0; mf < 4; ++mf)
        #pragma unroll
        for (int nf = 0; nf < 4; ++nf) acc[mf][nf] = f32x4{0.f, 0.f, 0.f, 0.f};

    // phase 2: Wf = t1 @ Wf2 + b2, K=256, M=64 (k in p-order, matches pWf2)
    for (int ks = 0; ks < 8; ++ks) {
        bf16x8 a[4];
        #pragma unroll
        for (int mf = 0; mf < 4; ++mf) {
            int row = mf * 16 + l15;
            a[mf] = *(const bf16x8*)(t1S + row * 512 + ((ks * 64 + q * 16) ^ ((row & 7) << 4)));
        }
        #pragma unroll
        for (int nf = 0; nf < 4; ++nf) {
            bf16x8 b = *(const bf16x8*)(pW + PO_WF2 + (((ks * 16 + w * 4 + nf) * 64) + lane) * 8);
            #pragma unroll
            for (int mf = 0; mf < 4; ++mf)
                acc[mf][nf] = __builtin_amdgcn_mfma_f32_16x16x32_bf16(a[mf], b, acc[mf][nf], 0, 0, 0);
        }
    }
    __syncthreads();   // t1S reads done; reuse region for h rows

    {   // stage h[colS[0..63]] (p-order rows) into LDS: 4 thr/row, 8x16B each
        int r = tid >> 2, ch = tid & 3;
        const short* hp = h + (size_t)colS[r] * NFF;
        int sw = (r & 7) << 4;
        #pragma unroll
        for (int i = 0; i < 8; ++i) {
            int chunk = ch + i * 4;          // 16B chunk index 0..31
            bf16x8 v = *(const bf16x8*)(hp + chunk * 8);
            *(bf16x8*)(t1S + r * 512 + ((chunk * 16) ^ sw)) = v;
        }
    }
    __syncthreads();

    // epilogue: msg[dest_e, p] = h[col_e, p] * Wf[e, p]; b64 in, b64 out
    {
        float bia[4];
        #pragma unroll
        for (int nf = 0; nf < 4; ++nf) bia[nf] = bf2v[w * 64 + nf * 16 + l15];
        #pragma unroll
        for (int mf = 0; mf < 4; ++mf) {
            #pragma unroll
            for (int r = 0; r < 4; ++r) {
                int eloc = mf * 16 + q * 4 + r;
                u32x2 hv = *(const u32x2*)(t1S + eloc * 512 + ((w * 128 + l15 * 8) ^ ((eloc & 7) << 4)));
                float m0 = bfu_lo(hv[0]) * (acc[mf][0][r] + bia[0]);
                float m1 = bfu_hi(hv[0]) * (acc[mf][1][r] + bia[1]);
                float m2 = bfu_lo(hv[1]) * (acc[mf][2][r] + bia[2]);
                float m3 = bfu_hi(hv[1]) * (acc[mf][3][r] + bia[3]);
                u32x2 out = {cvtpk(m0, m1), cvtpk(m2, m3)};
                *(u32x2*)(msg + (size_t)destS[eloc] * NFF + w * 64 + l15 * 4) = out;
            }
        }
    }
}

// ---- K3 fused: contiguous CSR segment-sum (p-order) + MFMA node GEMMs ----
__global__ __launch_bounds__(256) void k3_node(
        const short* __restrict__ msg, const int* __restrict__ rowptr,
        const short* __restrict__ pW, const float* __restrict__ bl2,
        const float* __restrict__ bl3,
        const float* __restrict__ x, float* __restrict__ xo) {
    __shared__ char aggS[32 * 512];  // [32][256] bf16 p-order, swizzled
    __shared__ char t2S[32 * 256];   // [32][128] bf16 p2-order, swizzled
    int n0 = blockIdx.x * 32;
    int tid = threadIdx.x;
    int lane = tid & 63, w = tid >> 6, q = lane >> 4, l15 = lane & 15;

    {   // segment-sum: 8 thr/node, 32 cols each; msg rows contiguous
        int nd = tid >> 3, c0 = (tid & 7) * 32;
        int n = n0 + nd;
        int p0 = 0, p1 = 0;
        if (n < NN) { p0 = rowptr[n]; p1 = rowptr[n + 1]; }
        float a[32];
        #pragma unroll
        for (int i = 0; i < 32; ++i) a[i] = 0.f;
        for (int p = p0; p < p1; ++p) {
            const short* mrow = msg + (size_t)p * NFF + c0;
            #pragma unroll
            for (int j = 0; j < 4; ++j) {
                u32x4 v = *(const u32x4*)(mrow + j * 8);
                #pragma unroll
                for (int k = 0; k < 4; ++k) {
                    a[j * 8 + 2 * k]     += bfu_lo(v[k]);
                    a[j * 8 + 2 * k + 1] += bfu_hi(v[k]);
                }
            }
        }
        int sw = (nd & 7) << 4;
        #pragma unroll
        for (int j = 0; j < 4; ++j) {
            u32x4 v = {cvtpk(a[j * 8 + 0], a[j * 8 + 1]), cvtpk(a[j * 8 + 2], a[j * 8 + 3]),
                       cvtpk(a[j * 8 + 4], a[j * 8 + 5]), cvtpk(a[j * 8 + 6], a[j * 8 + 7])};
            *(u32x4*)(aggS + nd * 512 + (((c0 + j * 8) * 2) ^ sw)) = v;
        }
    }
    __syncthreads();

    // GEMM1: t2 = ssp(agg @ Wl2 + b2), k in p-order (pWl2 matches)
    f32x4 acc[2][2];
    #pragma unroll
    for (int mf = 0; mf < 2; ++mf)
        #pragma unroll
        for (int nf = 0; nf < 2; ++nf) acc[mf][nf] = f32x4{0.f, 0.f, 0.f, 0.f};
    for (int ks = 0; ks < 8; ++ks) {
        bf16x8 a[2];
        #pragma unroll
        for (int mf = 0; mf < 2; ++mf) {
            int row = mf * 16 + l15;
            a[mf] = *(const bf16x8*)(aggS + row * 512 + ((ks * 64 + q * 16) ^ ((row & 7) << 4)));
        }
        #pragma unroll
        for (int nf = 0; nf < 2; ++nf) {
            bf16x8 b = *(const bf16x8*)(pW + PO_WL2 + (((ks * 8 + w * 2 + nf) * 64) + lane) * 8);
            #pragma unroll
            for (int mf = 0; mf < 2; ++mf)
                acc[mf][nf] = __builtin_amdgcn_mfma_f32_16x16x32_bf16(a[mf], b, acc[mf][nf], 0, 0, 0);
        }
    }
    {   // t2 in p2-order: b32 per (mf,r)
        float bia[2];
        #pragma unroll
        for (int nf = 0; nf < 2; ++nf) bia[nf] = bl2[w * 32 + nf * 16 + l15];
        #pragma unroll
        for (int mf = 0; mf < 2; ++mf) {
            #pragma unroll
            for (int r = 0; r < 4; ++r) {
                int row = mf * 16 + q * 4 + r;
                unsigned u = cvtpk(sspf(acc[mf][0][r] + bia[0]), sspf(acc[mf][1][r] + bia[1]));
                *(unsigned*)(t2S + row * 256 + ((w * 64 + l15 * 4) ^ ((row & 7) << 4))) = u;
            }
        }
    }
    __syncthreads();

    // GEMM2: y = t2 @ Wl3 + b3, k in p2-order (pWl3 matches)
    f32x4 acc2[2][2];
    #pragma unroll
    for (int mf = 0; mf < 2; ++mf)
        #pragma unroll
        for (int nf = 0; nf < 2; ++nf) acc2[mf][nf] = f32x4{0.f, 0.f, 0.f, 0.f};
    #pragma unroll
    for (int ks = 0; ks < 4; ++ks) {
        bf16x8 a[2];
        #pragma unroll
        for (int mf = 0; mf < 2; ++mf) {
            int row = mf * 16 + l15;
            a[mf] = *(const bf16x8*)(t2S + row * 256 + ((ks * 64 + q * 16) ^ ((row & 7) << 4)));
        }
        #pragma unroll
        for (int nf = 0; nf < 2; ++nf) {
            bf16x8 b = *(const bf16x8*)(pW + PO_WL3 + (((ks * 8 + w * 2 + nf) * 64) + lane) * 8);
            #pragma unroll
            for (int mf = 0; mf < 2; ++mf)
                acc2[mf][nf] = __builtin_amdgcn_mfma_f32_16x16x32_bf16(a[mf], b, acc2[mf][nf], 0, 0, 0);
        }
    }
    #pragma unroll
    for (int nf = 0; nf < 2; ++nf) {
        int col = w * 32 + nf * 16 + l15;
        float bias = bl3[col];
        #pragma unroll
        for (int mf = 0; mf < 2; ++mf) {
            #pragma unroll
            for (int r = 0; r < 4; ++r) {
                int n = n0 + mf * 16 + q * 4 + r;
                if (n < NN) {
                    size_t o = (size_t)n * CC + col;
                    xo[o] = fmaxf(acc2[mf][nf][r] + bias, 0.f) + x[o];
                }
            }
        }
    }
}

// ---- K4: MFMA e_out = tanh([ea | xo[row]+xo[col]] @ We + be) ----
__global__ __launch_bounds__(256) void k4_mfma(
        const float* __restrict__ ea, const int* __restrict__ eidx,
        const float* __restrict__ xo, const short* __restrict__ pW,
        const float* __restrict__ bev, float* __restrict__ eo) {
    __shared__ char aS[64 * 384];    // [64][192] bf16, swizzled
    int e0 = blockIdx.x * 64;
    int tid = threadIdx.x;
    int lane = tid & 63, w = tid >> 6;
    int q = lane >> 4, l15 = lane & 15;

    {   // stage ea (k 0..63)
        int r = tid >> 2, cp = tid & 3;
        const float4* src = (const float4*)(ea + (size_t)(e0 + r) * ECH + cp * 16);
        float4 f0 = src[0], f1 = src[1], f2 = src[2], f3 = src[3];
        u32x4 c0 = {cvtpk(f0.x, f0.y), cvtpk(f0.z, f0.w), cvtpk(f1.x, f1.y), cvtpk(f1.z, f1.w)};
        u32x4 c1 = {cvtpk(f2.x, f2.y), cvtpk(f2.z, f2.w), cvtpk(f3.x, f3.y), cvtpk(f3.z, f3.w)};
        int sw = (r & 7) << 4;
        *(u32x4*)(aS + r * 384 + ((cp * 32) ^ sw)) = c0;
        *(u32x4*)(aS + r * 384 + ((cp * 32 + 16) ^ sw)) = c1;
    }
    {   // stage xo[row]+xo[col] (k 64..191)
        int e = tid >> 2, p = tid & 3;
        int rr = eidx[e0 + e], cc = eidx[NE + e0 + e];
        const float4* xr = (const float4*)(xo + (size_t)rr * CC);
        const float4* xc = (const float4*)(xo + (size_t)cc * CC);
        int sw = (e & 7) << 4;
        #pragma unroll
        for (int it = 0; it < 8; ++it) {
            int fi = p + it * 4;
            float4 va = xr[fi], vb = xc[fi];
            u32x2 hv = {cvtpk(va.x + vb.x, va.y + vb.y), cvtpk(va.z + vb.z, va.w + vb.w)};
            int byte = (ECH + fi * 4) * 2;
            *(u32x2*)(aS + e * 384 + (byte ^ sw)) = hv;
        }
    }
    __syncthreads();

    f32x4 acc[8];
    #pragma unroll
    for (int nf = 0; nf < 8; ++nf) acc[nf] = f32x4{0.f, 0.f, 0.f, 0.f};

    #pragma unroll
    for (int ks = 0; ks < 6; ++ks) {
        int row = w * 16 + l15;
        bf16x8 a = *(const bf16x8*)(aS + row * 384 + ((ks * 64 + q * 16) ^ ((row & 7) << 4)));
        #pragma unroll
        for (int nf = 0; nf < 8; ++nf) {
            bf16x8 b = *(const bf16x8*)(pW + PO_WE + (((ks * 8 + nf) * 64) + lane) * 8);
            acc[nf] = __builtin_amdgcn_mfma_f32_16x16x32_bf16(a, b, acc[nf], 0, 0, 0);
        }
    }
    #pragma unroll
    for (int nf = 0; nf < 8; ++nf) {
        int col = nf * 16 + l15;
        float bias = bev[col];
        #pragma unroll
        for (int r = 0; r < 4; ++r) {
            int e = e0 + w * 16 + q * 4 + r;
            eo[(size_t)e * CC + col] = ftanh(acc[nf][r] + bias);
        }
    }
}

extern "C" void kernel_launch(void* const* d_in, const int* in_sizes, int n_in,
                              void* d_out, int out_size, void* d_ws, size_t ws_size,
                              hipStream_t stream) {
    const float* x   = (const float*)d_in[0];
    const int*   ei  = (const int*)d_in[1];
    const float* ea  = (const float*)d_in[2];
    const float* Wf1 = (const float*)d_in[4];
    const float* bf1 = (const float*)d_in[5];
    const float* Wf2 = (const float*)d_in[6];
    const float* bf2 = (const float*)d_in[7];
    const float* Wl1 = (const float*)d_in[8];
    const float* Wl2 = (const float*)d_in[9];
    const float* bl2 = (const float*)d_in[10];
    const float* Wl3 = (const float*)d_in[11];
    const float* bl3 = (const float*)d_in[12];
    const float* We  = (const float*)d_in[13];
    const float* be  = (const float*)d_in[14];

    float* xo = (float*)d_out;                 // [N, C] final
    float* eo = xo + (size_t)NN * CC;          // [E, C] final

    // region reuse (sequential lifetimes):
    short* h   = (short*)xo;   // bf16 [N,256] p-order, dead before k3 writes xo
    short* msg = (short*)eo;   // bf16 [E,256] p-order, dead before k4 writes eo

    // ws: [packed weights 384KB][dest E][cnt N][offw N][rowptr N+1][bsum 256]
    short* pW    = (short*)d_ws;
    int* dest    = (int*)((char*)d_ws + 393216);
    int* cnt     = dest + NE;
    int* offw    = cnt + NN;
    int* rowptr  = offw + NN;
    int* bsum    = rowptr + NN + 1;

    const int NB = (NN + 255) / 256;

    kpack<<<P_TOT / 256, 256, 0, stream>>>(Wf1, Wf2, We, Wl1, Wl2, Wl3, pW);
    k0_zero<<<49, 256, 0, stream>>>((float*)cnt, NN / 4);
    k_cnt<<<(NE + 255) / 256, 256, 0, stream>>>(ei, cnt);
    k_scan1<<<NB, 256, 0, stream>>>(cnt, offw, bsum);
    k_scan2<<<1, 256, 0, stream>>>(bsum, NB);
    k_scan3<<<NB, 256, 0, stream>>>(offw, bsum, rowptr);
    k_scatter<<<(NE + 255) / 256, 256, 0, stream>>>(ei, offw, dest);
    k1_h<<<(NN + 31) / 32, 256, 0, stream>>>(x, pW, h);
    k2a_msg<<<NE / 64, 256, 0, stream>>>(ea, ei, dest, pW, bf1, bf2, h, msg);
    k3_node<<<(NN + 31) / 32, 256, 0, stream>>>(msg, rowptr, pW, bl2, bl3, x, xo);
    k4_mfma<<<NE / 64, 256, 0, stream>>>(ea, ei, xo, pW, be, eo);
}

// Round 10
// 542.535 us; speedup vs baseline: 2.8716x; 1.0103x over previous
//
#include <hip/hip_runtime.h>

#define NN  50000
#define NE  600000
#define CC  128
#define NFF 256
#define ECH 64
#define EIN 192   // ECH + CC

typedef __attribute__((ext_vector_type(8))) short bf16x8;
typedef __attribute__((ext_vector_type(4))) short bf16x4;
typedef __attribute__((ext_vector_type(4))) float f32x4;
typedef __attribute__((ext_vector_type(4))) unsigned u32x4;
typedef __attribute__((ext_vector_type(2))) unsigned u32x2;

// fast shifted-softplus: softplus(v)-ln2 via hw exp/log
__device__ __forceinline__ float sspf(float v) {
    float e = __expf(-fabsf(v));
    return fmaxf(v, 0.f) + __logf(1.f + e) - 0.693147180559945f;
}
// fast tanh via hw exp
__device__ __forceinline__ float ftanh(float v) {
    float e = __expf(-2.f * fabsf(v));
    float r = (1.f - e) / (1.f + e);
    return copysignf(r, v);
}
__device__ __forceinline__ short bf16r(float f) {
    unsigned u = __float_as_uint(f);
    u = (u + 0x7FFFu + ((u >> 16) & 1u)) >> 16;
    return (short)u;
}
// packed fp32x2 -> bf16x2 (RNE), single VALU op
__device__ __forceinline__ unsigned cvtpk(float lo, float hi) {
    unsigned r;
    asm("v_cvt_pk_bf16_f32 %0, %1, %2" : "=v"(r) : "v"(lo), "v"(hi));
    return r;
}
__device__ __forceinline__ float bfu_lo(unsigned u) { return __uint_as_float(u << 16); }
__device__ __forceinline__ float bfu_hi(unsigned u) { return __uint_as_float(u & 0xffff0000u); }

// ---- pack ALL weights to bf16 fragment-linear layout for mfma_16x16x32 B-op.
// 256-col tensors (h, t1, agg) live in fragment order p = w*64 + l15*4 + nf;
// consumers' k-dims packed with orig_k(p) = (p>>6)*64+(p&3)*16+((p>>2)&15).
// 128-col t2 (k3-internal): p2 order, orig_k2(p) = (p>>5)*32+(p&1)*16+((p&31)>>1).
#define PO_WF1 0
#define PO_WF2 16384
#define PO_WE  81920
#define PO_WL1 106496
#define PO_WL2 139264
#define PO_WL3 172032
#define P_TOT  188416
__global__ void kpack(const float* __restrict__ Wf1, const float* __restrict__ Wf2,
                      const float* __restrict__ We,  const float* __restrict__ Wl1,
                      const float* __restrict__ Wl2, const float* __restrict__ Wl3,
                      short* __restrict__ p) {
    int i = blockIdx.x * 256 + threadIdx.x;
    if (i < PO_WF2) {                      // Wf1 [64][256]: k orig, n orig
        int t = i - PO_WF1;
        int j = t & 7, lane = (t >> 3) & 63, n16 = (t >> 9) & 15, ks = t >> 13;
        p[i] = bf16r(Wf1[(ks * 32 + (lane >> 4) * 8 + j) * NFF + n16 * 16 + (lane & 15)]);
    } else if (i < PO_WE) {                // Wf2 [256][256]: k in t1 p-order
        int t = i - PO_WF2;
        int j = t & 7, lane = (t >> 3) & 63, n16 = (t >> 9) & 15, ks = t >> 13;
        int kp = ks * 32 + (lane >> 4) * 8 + j;
        int k = (kp >> 6) * 64 + (kp & 3) * 16 + ((kp >> 2) & 15);
        p[i] = bf16r(Wf2[k * NFF + n16 * 16 + (lane & 15)]);
    } else if (i < PO_WL1) {               // We [192][128]: k orig, n orig
        int t = i - PO_WE;
        int j = t & 7, lane = (t >> 3) & 63, n16 = (t >> 9) & 7, ks = t >> 12;
        p[i] = bf16r(We[(ks * 32 + (lane >> 4) * 8 + j) * CC + n16 * 16 + (lane & 15)]);
    } else if (i < PO_WL2) {               // Wl1 [128][256]: k orig, n orig
        int t = i - PO_WL1;
        int j = t & 7, lane = (t >> 3) & 63, n16 = (t >> 9) & 15, ks = t >> 13;
        p[i] = bf16r(Wl1[(ks * 32 + (lane >> 4) * 8 + j) * NFF + n16 * 16 + (lane & 15)]);
    } else if (i < PO_WL3) {               // Wl2 [256][128]: k in agg p-order
        int t = i - PO_WL2;
        int j = t & 7, lane = (t >> 3) & 63, n16 = (t >> 9) & 7, ks = t >> 12;
        int kp = ks * 32 + (lane >> 4) * 8 + j;
        int k = (kp >> 6) * 64 + (kp & 3) * 16 + ((kp >> 2) & 15);
        p[i] = bf16r(Wl2[k * CC + n16 * 16 + (lane & 15)]);
    } else if (i < P_TOT) {                // Wl3 [128][128]: k in t2 p2-order
        int t = i - PO_WL3;
        int j = t & 7, lane = (t >> 3) & 63, n16 = (t >> 9) & 7, ks = t >> 12;
        int kp = ks * 32 + (lane >> 4) * 8 + j;
        int k = (kp >> 5) * 32 + (kp & 1) * 16 + ((kp & 31) >> 1);
        p[i] = bf16r(Wl3[k * CC + n16 * 16 + (lane & 15)]);
    }
}

// ---- K0: zero ----
__global__ void k0_zero(float* __restrict__ p, long n4) {
    long i = (long)blockIdx.x * blockDim.x + threadIdx.x;
    long stride = (long)gridDim.x * blockDim.x;
    float4 z = {0.f, 0.f, 0.f, 0.f};
    for (; i < n4; i += stride) ((float4*)p)[i] = z;
}

// ---- CSR build ----
__global__ void k_cnt(const int* __restrict__ eidx, int* __restrict__ cnt) {
    int e = blockIdx.x * 256 + threadIdx.x;
    if (e < NE) atomicAdd(&cnt[eidx[e]], 1);
}

__global__ __launch_bounds__(256) void k_scan1(const int* __restrict__ cnt,
                                               int* __restrict__ offw,
                                               int* __restrict__ bsum) {
    __shared__ int sw_[4];
    int i = blockIdx.x * 256 + threadIdx.x;
    int lane = threadIdx.x & 63, wv = threadIdx.x >> 6;
    int v = (i < NN) ? cnt[i] : 0;
    int inc = v;
    #pragma unroll
    for (int d = 1; d < 64; d <<= 1) {
        int t = __shfl_up(inc, d, 64);
        if (lane >= d) inc += t;
    }
    if (lane == 63) sw_[wv] = inc;
    __syncthreads();
    int woff = 0;
    #pragma unroll
    for (int k = 0; k < 4; ++k) woff += (k < wv) ? sw_[k] : 0;
    if (i < NN) offw[i] = woff + inc - v;
    if (threadIdx.x == 255) bsum[blockIdx.x] = woff + inc;
}

__global__ __launch_bounds__(256) void k_scan2(int* __restrict__ bsum, int nb) {
    __shared__ int sw_[4];
    int t = threadIdx.x;
    int lane = t & 63, wv = t >> 6;
    int v = (t < nb) ? bsum[t] : 0;
    int inc = v;
    #pragma unroll
    for (int d = 1; d < 64; d <<= 1) {
        int s = __shfl_up(inc, d, 64);
        if (lane >= d) inc += s;
    }
    if (lane == 63) sw_[wv] = inc;
    __syncthreads();
    int woff = 0;
    #pragma unroll
    for (int k = 0; k < 4; ++k) woff += (k < wv) ? sw_[k] : 0;
    if (t < nb) bsum[t] = woff + inc - v;
}

__global__ void k_scan3(int* __restrict__ offw, const int* __restrict__ bsum,
                        int* __restrict__ rowptr) {
    int i = blockIdx.x * 256 + threadIdx.x;
    if (i < NN) {
        int v = offw[i] + bsum[blockIdx.x];
        offw[i] = v;
        rowptr[i] = v;
    }
    if (i == 0) rowptr[NN] = NE;
}

// ---- scatter: physically permute edges into row-sorted order (bf16 ea_s) ----
__global__ void k_scatter(const int* __restrict__ eidx, const float* __restrict__ ea,
                          int* __restrict__ offw, short* __restrict__ ea_s,
                          int* __restrict__ col_s, int* __restrict__ row_s) {
    int e = blockIdx.x * 256 + threadIdx.x;
    if (e >= NE) return;
    int r = eidx[e], c = eidx[NE + e];
    int pos = atomicAdd(&offw[r], 1);
    col_s[pos] = c;
    row_s[pos] = r;
    const float4* src = (const float4*)(ea + (size_t)e * ECH);
    short* dst = ea_s + (size_t)pos * ECH;
    #pragma unroll
    for (int i = 0; i < 4; ++i) {
        float4 f0 = src[4 * i], f1 = src[4 * i + 1], f2 = src[4 * i + 2], f3 = src[4 * i + 3];
        u32x4 v0 = {cvtpk(f0.x, f0.y), cvtpk(f0.z, f0.w), cvtpk(f1.x, f1.y), cvtpk(f1.z, f1.w)};
        u32x4 v1 = {cvtpk(f2.x, f2.y), cvtpk(f2.z, f2.w), cvtpk(f3.x, f3.y), cvtpk(f3.z, f3.w)};
        *(u32x4*)(dst + i * 16) = v0;
        *(u32x4*)(dst + i * 16 + 8) = v1;
    }
}

// ---- K1: h[N,256] = x @ Wl1 (MFMA), h stored in p-order ----
__global__ __launch_bounds__(256) void k1_h(const float* __restrict__ x,
                                            const short* __restrict__ pW,
                                            short* __restrict__ h) {
    __shared__ char xS[32 * 256];   // [32][128] bf16, swizzled
    int n0 = blockIdx.x * 32;
    int tid = threadIdx.x;
    int lane = tid & 63, w = tid >> 6, q = lane >> 4, l15 = lane & 15;
    {
        int r = tid >> 3, seg = tid & 7;
        int rr = min(n0 + r, NN - 1);
        const float4* src = (const float4*)(x + (size_t)rr * CC + seg * 16);
        float4 f0 = src[0], f1 = src[1], f2 = src[2], f3 = src[3];
        u32x4 c0 = {cvtpk(f0.x, f0.y), cvtpk(f0.z, f0.w), cvtpk(f1.x, f1.y), cvtpk(f1.z, f1.w)};
        u32x4 c1 = {cvtpk(f2.x, f2.y), cvtpk(f2.z, f2.w), cvtpk(f3.x, f3.y), cvtpk(f3.z, f3.w)};
        int sw = (r & 7) << 4;
        *(u32x4*)(xS + r * 256 + ((seg * 32) ^ sw)) = c0;
        *(u32x4*)(xS + r * 256 + ((seg * 32 + 16) ^ sw)) = c1;
    }
    __syncthreads();

    f32x4 acc[2][4];
    #pragma unroll
    for (int mf = 0; mf < 2; ++mf)
        #pragma unroll
        for (int nf = 0; nf < 4; ++nf) acc[mf][nf] = f32x4{0.f, 0.f, 0.f, 0.f};

    #pragma unroll
    for (int ks = 0; ks < 4; ++ks) {
        bf16x8 a[2];
        #pragma unroll
        for (int mf = 0; mf < 2; ++mf) {
            int row = mf * 16 + l15;
            a[mf] = *(const bf16x8*)(xS + row * 256 + ((ks * 64 + q * 16) ^ ((row & 7) << 4)));
        }
        #pragma unroll
        for (int nf = 0; nf < 4; ++nf) {
            bf16x8 b = *(const bf16x8*)(pW + PO_WL1 + (((ks * 16 + w * 4 + nf) * 64) + lane) * 8);
            #pragma unroll
            for (int mf = 0; mf < 2; ++mf)
                acc[mf][nf] = __builtin_amdgcn_mfma_f32_16x16x32_bf16(a[mf], b, acc[mf][nf], 0, 0, 0);
        }
    }
    #pragma unroll
    for (int mf = 0; mf < 2; ++mf) {
        #pragma unroll
        for (int r = 0; r < 4; ++r) {
            int n = n0 + mf * 16 + q * 4 + r;
            if (n < NN) {
                u32x2 v = {cvtpk(acc[mf][0][r], acc[mf][1][r]),
                           cvtpk(acc[mf][2][r], acc[mf][3][r])};
                *(u32x2*)(h + (size_t)n * NFF + w * 64 + l15 * 4) = v;
            }
        }
    }
}

// ---- K2b: FUSED filter-net + modulate + in-LDS segment-reduce -> agg fp32 ----
// 64 sorted slots/block, 4 waves; wave w owns cols [w*64, w*64+64).
// ea_s read direct-from-global (coalesced bf16); h modulated in place in LDS;
// 128 threads walk the tile per col-pair; interior nodes direct-store, boundary atomic.
__global__ __launch_bounds__(256, 4) void k2b_agg(
        const short* __restrict__ ea_s, const int* __restrict__ col_s,
        const int* __restrict__ row_s,
        const short* __restrict__ pW, const float* __restrict__ bf1v,
        const float* __restrict__ bf2v,
        const short* __restrict__ h, float* __restrict__ agg) {
    __shared__ char t1S[64 * 512];   // t1 p-order -> h rows -> msg tile (in place)
    __shared__ int colS[64], rowS[64];
    int s0 = blockIdx.x * 64;
    int tid = threadIdx.x;
    int lane = tid & 63, w = tid >> 6;
    int q = lane >> 4, l15 = lane & 15;

    if (tid < 64) {
        colS[tid] = col_s[s0 + tid];
        rowS[tid] = row_s[s0 + tid];
    }

    f32x4 acc[4][4];
    #pragma unroll
    for (int mf = 0; mf < 4; ++mf)
        #pragma unroll
        for (int nf = 0; nf < 4; ++nf) acc[mf][nf] = f32x4{0.f, 0.f, 0.f, 0.f};

    // phase 1: t1 = ssp(ea_s @ Wf1 + b1), K=64, M=64; A direct from global bf16
    #pragma unroll
    for (int ks = 0; ks < 2; ++ks) {
        bf16x8 a[4];
        #pragma unroll
        for (int mf = 0; mf < 4; ++mf)
            a[mf] = *(const bf16x8*)(ea_s + (size_t)(s0 + mf * 16 + l15) * ECH + ks * 32 + q * 8);
        #pragma unroll
        for (int nf = 0; nf < 4; ++nf) {
            bf16x8 b = *(const bf16x8*)(pW + PO_WF1 + (((ks * 16 + w * 4 + nf) * 64) + lane) * 8);
            #pragma unroll
            for (int mf = 0; mf < 4; ++mf)
                acc[mf][nf] = __builtin_amdgcn_mfma_f32_16x16x32_bf16(a[mf], b, acc[mf][nf], 0, 0, 0);
        }
    }
    // ssp + bias, write t1 in p-order: b64 per (mf,r)
    {
        float bia[4];
        #pragma unroll
        for (int nf = 0; nf < 4; ++nf) bia[nf] = bf1v[w * 64 + nf * 16 + l15];
        #pragma unroll
        for (int mf = 0; mf < 4; ++mf) {
            #pragma unroll
            for (int r = 0; r < 4; ++r) {
                int row = mf * 16 + q * 4 + r;
                u32x2 v = {cvtpk(sspf(acc[mf][0][r] + bia[0]), sspf(acc[mf][1][r] + bia[1])),
                           cvtpk(sspf(acc[mf][2][r] + bia[2]), sspf(acc[mf][3][r] + bia[3]))};
                *(u32x2*)(t1S + row * 512 + ((w * 128 + l15 * 8) ^ ((row & 7) << 4))) = v;
            }
        }
    }
    __syncthreads();

    #pragma unroll
    for (int mf = 0; mf < 4; ++mf)
        #pragma unroll
        for (int nf = 0; nf < 4; ++nf) acc[mf][nf] = f32x4{0.f, 0.f, 0.f, 0.f};

    // phase 2: Wf = t1 @ Wf2 + b2, K=256, M=64 (k in p-order)
    for (int ks = 0; ks < 8; ++ks) {
        bf16x8 a[4];
        #pragma unroll
        for (int mf = 0; mf < 4; ++mf) {
            int row = mf * 16 + l15;
            a[mf] = *(const bf16x8*)(t1S + row * 512 + ((ks * 64 + q * 16) ^ ((row & 7) << 4)));
        }
        #pragma unroll
        for (int nf = 0; nf < 4; ++nf) {
            bf16x8 b = *(const bf16x8*)(pW + PO_WF2 + (((ks * 16 + w * 4 + nf) * 64) + lane) * 8);
            #pragma unroll
            for (int mf = 0; mf < 4; ++mf)
                acc[mf][nf] = __builtin_amdgcn_mfma_f32_16x16x32_bf16(a[mf], b, acc[mf][nf], 0, 0, 0);
        }
    }
    __syncthreads();   // t1S reads done; reuse region for h rows

    {   // stage h[colS[0..63]] (p-order rows) into LDS: 4 thr/row, 8x16B each
        int r = tid >> 2, ch = tid & 3;
        const short* hp = h + (size_t)colS[r] * NFF;
        int sw = (r & 7) << 4;
        #pragma unroll
        for (int i = 0; i < 8; ++i) {
            int chunk = ch + i * 4;
            bf16x8 v = *(const bf16x8*)(hp + chunk * 8);
            *(bf16x8*)(t1S + r * 512 + ((chunk * 16) ^ sw)) = v;
        }
    }
    __syncthreads();

    // in-place modulate: t1S[eloc][p-pair] = h * Wf  (each addr owned by one thread)
    {
        float bia[4];
        #pragma unroll
        for (int nf = 0; nf < 4; ++nf) bia[nf] = bf2v[w * 64 + nf * 16 + l15];
        #pragma unroll
        for (int mf = 0; mf < 4; ++mf) {
            #pragma unroll
            for (int r = 0; r < 4; ++r) {
                int eloc = mf * 16 + q * 4 + r;
                char* addr = t1S + eloc * 512 + ((w * 128 + l15 * 8) ^ ((eloc & 7) << 4));
                u32x2 hv = *(const u32x2*)addr;
                float m0 = bfu_lo(hv[0]) * (acc[mf][0][r] + bia[0]);
                float m1 = bfu_hi(hv[0]) * (acc[mf][1][r] + bia[1]);
                float m2 = bfu_lo(hv[1]) * (acc[mf][2][r] + bia[2]);
                float m3 = bfu_hi(hv[1]) * (acc[mf][3][r] + bia[3]);
                u32x2 out = {cvtpk(m0, m1), cvtpk(m2, m3)};
                *(u32x2*)addr = out;
            }
        }
    }
    __syncthreads();

    // segment-reduce: 128 threads, thread cp owns cols (2cp, 2cp+1) in p-order.
    // Walk 64 sorted slots; node change -> emit. Interior segment (astart>0,
    // end<63) is written exactly once -> direct store; boundary -> atomicAdd.
    if (tid < 128) {
        int cp = tid;
        float a0 = 0.f, a1 = 0.f;
        int cur = rowS[0];
        int astart = 0;
        for (int e = 0; e < 64; ++e) {
            int rw = rowS[e];
            if (rw != cur) {
                float* dst = agg + (size_t)cur * NFF + cp * 2;
                if (astart > 0) {           // interior: e-1 <= 62 always
                    dst[0] = a0; dst[1] = a1;
                } else {
                    atomicAdd(dst, a0); atomicAdd(dst + 1, a1);
                }
                a0 = 0.f; a1 = 0.f;
                cur = rw;
                astart = e;
            }
            unsigned v = *(const unsigned*)(t1S + e * 512 + ((cp * 4) ^ ((e & 7) << 4)));
            a0 += bfu_lo(v);
            a1 += bfu_hi(v);
        }
        // final segment ends at slot 63 -> always boundary
        float* dst = agg + (size_t)cur * NFF + cp * 2;
        atomicAdd(dst, a0); atomicAdd(dst + 1, a1);
    }
}

// ---- K3: load agg (fp32, p-order) + MFMA node GEMMs ----
__global__ __launch_bounds__(256) void k3_node(
        const float* __restrict__ agg,
        const short* __restrict__ pW, const float* __restrict__ bl2,
        const float* __restrict__ bl3,
        const float* __restrict__ x, float* __restrict__ xo) {
    __shared__ char aggS[32 * 512];  // [32][256] bf16 p-order, swizzled
    __shared__ char t2S[32 * 256];   // [32][128] bf16 p2-order, swizzled
    int n0 = blockIdx.x * 32;
    int tid = threadIdx.x;
    int lane = tid & 63, w = tid >> 6, q = lane >> 4, l15 = lane & 15;

    {   // coalesced agg load: 8 thr/node, 32 cols each
        int nd = tid >> 3, c0 = (tid & 7) * 32;
        int n = n0 + nd;
        float a[32];
        if (n < NN) {
            const float4* src = (const float4*)(agg + (size_t)n * NFF + c0);
            #pragma unroll
            for (int j = 0; j < 8; ++j) {
                float4 v = src[j];
                a[4 * j] = v.x; a[4 * j + 1] = v.y; a[4 * j + 2] = v.z; a[4 * j + 3] = v.w;
            }
        } else {
            #pragma unroll
            for (int i = 0; i < 32; ++i) a[i] = 0.f;
        }
        int sw = (nd & 7) << 4;
        #pragma unroll
        for (int j = 0; j < 4; ++j) {
            u32x4 v = {cvtpk(a[j * 8 + 0], a[j * 8 + 1]), cvtpk(a[j * 8 + 2], a[j * 8 + 3]),
                       cvtpk(a[j * 8 + 4], a[j * 8 + 5]), cvtpk(a[j * 8 + 6], a[j * 8 + 7])};
            *(u32x4*)(aggS + nd * 512 + (((c0 + j * 8) * 2) ^ sw)) = v;
        }
    }
    __syncthreads();

    // GEMM1: t2 = ssp(agg @ Wl2 + b2), k in p-order (pWl2 matches)
    f32x4 acc[2][2];
    #pragma unroll
    for (int mf = 0; mf < 2; ++mf)
        #pragma unroll
        for (int nf = 0; nf < 2; ++nf) acc[mf][nf] = f32x4{0.f, 0.f, 0.f, 0.f};
    for (int ks = 0; ks < 8; ++ks) {
        bf16x8 a[2];
        #pragma unroll
        for (int mf = 0; mf < 2; ++mf) {
            int row = mf * 16 + l15;
            a[mf] = *(const bf16x8*)(aggS + row * 512 + ((ks * 64 + q * 16) ^ ((row & 7) << 4)));
        }
        #pragma unroll
        for (int nf = 0; nf < 2; ++nf) {
            bf16x8 b = *(const bf16x8*)(pW + PO_WL2 + (((ks * 8 + w * 2 + nf) * 64) + lane) * 8);
            #pragma unroll
            for (int mf = 0; mf < 2; ++mf)
                acc[mf][nf] = __builtin_amdgcn_mfma_f32_16x16x32_bf16(a[mf], b, acc[mf][nf], 0, 0, 0);
        }
    }
    {   // t2 in p2-order: b32 per (mf,r)
        float bia[2];
        #pragma unroll
        for (int nf = 0; nf < 2; ++nf) bia[nf] = bl2[w * 32 + nf * 16 + l15];
        #pragma unroll
        for (int mf = 0; mf < 2; ++mf) {
            #pragma unroll
            for (int r = 0; r < 4; ++r) {
                int row = mf * 16 + q * 4 + r;
                unsigned u = cvtpk(sspf(acc[mf][0][r] + bia[0]), sspf(acc[mf][1][r] + bia[1]));
                *(unsigned*)(t2S + row * 256 + ((w * 64 + l15 * 4) ^ ((row & 7) << 4))) = u;
            }
        }
    }
    __syncthreads();

    // GEMM2: y = t2 @ Wl3 + b3, k in p2-order (pWl3 matches)
    f32x4 acc2[2][2];
    #pragma unroll
    for (int mf = 0; mf < 2; ++mf)
        #pragma unroll
        for (int nf = 0; nf < 2; ++nf) acc2[mf][nf] = f32x4{0.f, 0.f, 0.f, 0.f};
    #pragma unroll
    for (int ks = 0; ks < 4; ++ks) {
        bf16x8 a[2];
        #pragma unroll
        for (int mf = 0; mf < 2; ++mf) {
            int row = mf * 16 + l15;
            a[mf] = *(const bf16x8*)(t2S + row * 256 + ((ks * 64 + q * 16) ^ ((row & 7) << 4)));
        }
        #pragma unroll
        for (int nf = 0; nf < 2; ++nf) {
            bf16x8 b = *(const bf16x8*)(pW + PO_WL3 + (((ks * 8 + w * 2 + nf) * 64) + lane) * 8);
            #pragma unroll
            for (int mf = 0; mf < 2; ++mf)
                acc2[mf][nf] = __builtin_amdgcn_mfma_f32_16x16x32_bf16(a[mf], b, acc2[mf][nf], 0, 0, 0);
        }
    }
    #pragma unroll
    for (int nf = 0; nf < 2; ++nf) {
        int col = w * 32 + nf * 16 + l15;
        float bias = bl3[col];
        #pragma unroll
        for (int mf = 0; mf < 2; ++mf) {
            #pragma unroll
            for (int r = 0; r < 4; ++r) {
                int n = n0 + mf * 16 + q * 4 + r;
                if (n < NN) {
                    size_t o = (size_t)n * CC + col;
                    xo[o] = fmaxf(acc2[mf][nf][r] + bias, 0.f) + x[o];
                }
            }
        }
    }
}

// ---- K4: MFMA e_out = tanh([ea | xo[row]+xo[col]] @ We + be) ----
__global__ __launch_bounds__(256) void k4_mfma(
        const float* __restrict__ ea, const int* __restrict__ eidx,
        const float* __restrict__ xo, const short* __restrict__ pW,
        const float* __restrict__ bev, float* __restrict__ eo) {
    __shared__ char aS[64 * 384];    // [64][192] bf16, swizzled
    int e0 = blockIdx.x * 64;
    int tid = threadIdx.x;
    int lane = tid & 63, w = tid >> 6;
    int q = lane >> 4, l15 = lane & 15;

    {   // stage ea (k 0..63)
        int r = tid >> 2, cp = tid & 3;
        const float4* src = (const float4*)(ea + (size_t)(e0 + r) * ECH + cp * 16);
        float4 f0 = src[0], f1 = src[1], f2 = src[2], f3 = src[3];
        u32x4 c0 = {cvtpk(f0.x, f0.y), cvtpk(f0.z, f0.w), cvtpk(f1.x, f1.y), cvtpk(f1.z, f1.w)};
        u32x4 c1 = {cvtpk(f2.x, f2.y), cvtpk(f2.z, f2.w), cvtpk(f3.x, f3.y), cvtpk(f3.z, f3.w)};
        int sw = (r & 7) << 4;
        *(u32x4*)(aS + r * 384 + ((cp * 32) ^ sw)) = c0;
        *(u32x4*)(aS + r * 384 + ((cp * 32 + 16) ^ sw)) = c1;
    }
    {   // stage xo[row]+xo[col] (k 64..191)
        int e = tid >> 2, p = tid & 3;
        int rr = eidx[e0 + e], cc = eidx[NE + e0 + e];
        const float4* xr = (const float4*)(xo + (size_t)rr * CC);
        const float4* xc = (const float4*)(xo + (size_t)cc * CC);
        int sw = (e & 7) << 4;
        #pragma unroll
        for (int it = 0; it < 8; ++it) {
            int fi = p + it * 4;
            float4 va = xr[fi], vb = xc[fi];
            u32x2 hv = {cvtpk(va.x + vb.x, va.y + vb.y), cvtpk(va.z + vb.z, va.w + vb.w)};
            int byte = (ECH + fi * 4) * 2;
            *(u32x2*)(aS + e * 384 + (byte ^ sw)) = hv;
        }
    }
    __syncthreads();

    f32x4 acc[8];
    #pragma unroll
    for (int nf = 0; nf < 8; ++nf) acc[nf] = f32x4{0.f, 0.f, 0.f, 0.f};

    #pragma unroll
    for (int ks = 0; ks < 6; ++ks) {
        int row = w * 16 + l15;
        bf16x8 a = *(const bf16x8*)(aS + row * 384 + ((ks * 64 + q * 16) ^ ((row & 7) << 4)));
        #pragma unroll
        for (int nf = 0; nf < 8; ++nf) {
            bf16x8 b = *(const bf16x8*)(pW + PO_WE + (((ks * 8 + nf) * 64) + lane) * 8);
            acc[nf] = __builtin_amdgcn_mfma_f32_16x16x32_bf16(a, b, acc[nf], 0, 0, 0);
        }
    }
    #pragma unroll
    for (int nf = 0; nf < 8; ++nf) {
        int col = nf * 16 + l15;
        float bias = bev[col];
        #pragma unroll
        for (int r = 0; r < 4; ++r) {
            int e = e0 + w * 16 + q * 4 + r;
            eo[(size_t)e * CC + col] = ftanh(acc[nf][r] + bias);
        }
    }
}

extern "C" void kernel_launch(void* const* d_in, const int* in_sizes, int n_in,
                              void* d_out, int out_size, void* d_ws, size_t ws_size,
                              hipStream_t stream) {
    const float* x   = (const float*)d_in[0];
    const int*   ei  = (const int*)d_in[1];
    const float* ea  = (const float*)d_in[2];
    const float* Wf1 = (const float*)d_in[4];
    const float* bf1 = (const float*)d_in[5];
    const float* Wf2 = (const float*)d_in[6];
    const float* bf2 = (const float*)d_in[7];
    const float* Wl1 = (const float*)d_in[8];
    const float* Wl2 = (const float*)d_in[9];
    const float* bl2 = (const float*)d_in[10];
    const float* Wl3 = (const float*)d_in[11];
    const float* bl3 = (const float*)d_in[12];
    const float* We  = (const float*)d_in[13];
    const float* be  = (const float*)d_in[14];

    float* xo = (float*)d_out;                 // [N, C] final
    float* eo = xo + (size_t)NN * CC;          // [E, C] final

    // region reuse (sequential lifetimes, fully rewritten each call):
    //   h    bf16 [N,256] p-order in the xo region (dead before k3 writes xo)
    //   ea_s/col_s/row_s/agg carved from the TAIL of the eo region
    //   (all dead before k4 writes eo; k3 reads agg before k4 runs)
    short* h    = (short*)xo;                                  // 25.6 MB
    char*  top  = (char*)d_out + (size_t)out_size * sizeof(float);
    short* ea_s = (short*)(top - (size_t)NE * ECH * 2);        // 76.8 MB
    int*   col_s = (int*)((char*)ea_s - (size_t)NE * 4);       // 2.4 MB
    int*   row_s = (int*)((char*)col_s - (size_t)NE * 4);      // 2.4 MB
    float* agg  = (float*)((char*)row_s - (size_t)NN * NFF * 4); // 51.2 MB

    // ws: [packed weights 384KB][cnt N][offw N][rowptr N+1][bsum 256]
    short* pW    = (short*)d_ws;
    int* cnt     = (int*)((char*)d_ws + 393216);
    int* offw    = cnt + NN;
    int* rowptr  = offw + NN;
    int* bsum    = rowptr + NN + 1;

    const int NB = (NN + 255) / 256;

    kpack<<<P_TOT / 256, 256, 0, stream>>>(Wf1, Wf2, We, Wl1, Wl2, Wl3, pW);
    k0_zero<<<1024, 256, 0, stream>>>(agg, (long)NN * NFF / 4);
    k0_zero<<<49, 256, 0, stream>>>((float*)cnt, NN / 4);
    k_cnt<<<(NE + 255) / 256, 256, 0, stream>>>(ei, cnt);
    k_scan1<<<NB, 256, 0, stream>>>(cnt, offw, bsum);
    k_scan2<<<1, 256, 0, stream>>>(bsum, NB);
    k_scan3<<<NB, 256, 0, stream>>>(offw, bsum, rowptr);
    k_scatter<<<(NE + 255) / 256, 256, 0, stream>>>(ei, ea, offw, ea_s, col_s, row_s);
    k1_h<<<(NN + 31) / 32, 256, 0, stream>>>(x, pW, h);
    k2b_agg<<<NE / 64, 256, 0, stream>>>(ea_s, col_s, row_s, pW, bf1, bf2, h, agg);
    k3_node<<<(NN + 31) / 32, 256, 0, stream>>>(agg, pW, bl2, bl3, x, xo);
    k4_mfma<<<NE / 64, 256, 0, stream>>>(ea, ei, xo, pW, be, eo);
}

// Round 11
// 525.491 us; speedup vs baseline: 2.9647x; 1.0324x over previous
//
#include <hip/hip_runtime.h>

#define NN  50000
#define NE  600000
#define CC  128
#define NFF 256
#define ECH 64
#define EIN 192   // ECH + CC

typedef __attribute__((ext_vector_type(8))) short bf16x8;
typedef __attribute__((ext_vector_type(4))) short bf16x4;
typedef __attribute__((ext_vector_type(4))) float f32x4;
typedef __attribute__((ext_vector_type(4))) unsigned u32x4;
typedef __attribute__((ext_vector_type(2))) unsigned u32x2;

// fast shifted-softplus: softplus(v)-ln2 via hw exp/log
__device__ __forceinline__ float sspf(float v) {
    float e = __expf(-fabsf(v));
    return fmaxf(v, 0.f) + __logf(1.f + e) - 0.693147180559945f;
}
// fast tanh via hw exp
__device__ __forceinline__ float ftanh(float v) {
    float e = __expf(-2.f * fabsf(v));
    float r = (1.f - e) / (1.f + e);
    return copysignf(r, v);
}
__device__ __forceinline__ short bf16r(float f) {
    unsigned u = __float_as_uint(f);
    u = (u + 0x7FFFu + ((u >> 16) & 1u)) >> 16;
    return (short)u;
}
// packed fp32x2 -> bf16x2 (RNE), single VALU op
__device__ __forceinline__ unsigned cvtpk(float lo, float hi) {
    unsigned r;
    asm("v_cvt_pk_bf16_f32 %0, %1, %2" : "=v"(r) : "v"(lo), "v"(hi));
    return r;
}
__device__ __forceinline__ float bfu_lo(unsigned u) { return __uint_as_float(u << 16); }
__device__ __forceinline__ float bfu_hi(unsigned u) { return __uint_as_float(u & 0xffff0000u); }

// ---- pack ALL weights to bf16 fragment-linear layout for mfma_16x16x32 B-op.
// 256-col tensors (h, t1, agg) live in fragment order p = w*64 + l15*4 + nf;
// consumers' k-dims packed with orig_k(p) = (p>>6)*64+(p&3)*16+((p>>2)&15).
// 128-col t2 (k3-internal): p2 order, orig_k2(p) = (p>>5)*32+(p&1)*16+((p&31)>>1).
#define PO_WF1 0
#define PO_WF2 16384
#define PO_WE  81920
#define PO_WL1 106496
#define PO_WL2 139264
#define PO_WL3 172032
#define P_TOT  188416
__global__ void kpack(const float* __restrict__ Wf1, const float* __restrict__ Wf2,
                      const float* __restrict__ We,  const float* __restrict__ Wl1,
                      const float* __restrict__ Wl2, const float* __restrict__ Wl3,
                      short* __restrict__ p) {
    int i = blockIdx.x * 256 + threadIdx.x;
    if (i < PO_WF2) {                      // Wf1 [64][256]: k orig, n orig
        int t = i - PO_WF1;
        int j = t & 7, lane = (t >> 3) & 63, n16 = (t >> 9) & 15, ks = t >> 13;
        p[i] = bf16r(Wf1[(ks * 32 + (lane >> 4) * 8 + j) * NFF + n16 * 16 + (lane & 15)]);
    } else if (i < PO_WE) {                // Wf2 [256][256]: k in t1 p-order
        int t = i - PO_WF2;
        int j = t & 7, lane = (t >> 3) & 63, n16 = (t >> 9) & 15, ks = t >> 13;
        int kp = ks * 32 + (lane >> 4) * 8 + j;
        int k = (kp >> 6) * 64 + (kp & 3) * 16 + ((kp >> 2) & 15);
        p[i] = bf16r(Wf2[k * NFF + n16 * 16 + (lane & 15)]);
    } else if (i < PO_WL1) {               // We [192][128]: k orig, n orig
        int t = i - PO_WE;
        int j = t & 7, lane = (t >> 3) & 63, n16 = (t >> 9) & 7, ks = t >> 12;
        p[i] = bf16r(We[(ks * 32 + (lane >> 4) * 8 + j) * CC + n16 * 16 + (lane & 15)]);
    } else if (i < PO_WL2) {               // Wl1 [128][256]: k orig, n orig
        int t = i - PO_WL1;
        int j = t & 7, lane = (t >> 3) & 63, n16 = (t >> 9) & 15, ks = t >> 13;
        p[i] = bf16r(Wl1[(ks * 32 + (lane >> 4) * 8 + j) * NFF + n16 * 16 + (lane & 15)]);
    } else if (i < PO_WL3) {               // Wl2 [256][128]: k in agg p-order
        int t = i - PO_WL2;
        int j = t & 7, lane = (t >> 3) & 63, n16 = (t >> 9) & 7, ks = t >> 12;
        int kp = ks * 32 + (lane >> 4) * 8 + j;
        int k = (kp >> 6) * 64 + (kp & 3) * 16 + ((kp >> 2) & 15);
        p[i] = bf16r(Wl2[k * CC + n16 * 16 + (lane & 15)]);
    } else if (i < P_TOT) {                // Wl3 [128][128]: k in t2 p2-order
        int t = i - PO_WL3;
        int j = t & 7, lane = (t >> 3) & 63, n16 = (t >> 9) & 7, ks = t >> 12;
        int kp = ks * 32 + (lane >> 4) * 8 + j;
        int k = (kp >> 5) * 32 + (kp & 1) * 16 + ((kp & 31) >> 1);
        p[i] = bf16r(Wl3[k * CC + n16 * 16 + (lane & 15)]);
    }
}

// ---- K0: zero two regions in one launch (grid-stride) ----
__global__ void k0_zero2(float* __restrict__ p0, long n40,
                         float* __restrict__ p1, long n41) {
    long i = (long)blockIdx.x * blockDim.x + threadIdx.x;
    long stride = (long)gridDim.x * blockDim.x;
    float4 z = {0.f, 0.f, 0.f, 0.f};
    for (long k = i; k < n40; k += stride) ((float4*)p0)[k] = z;
    for (long k = i; k < n41; k += stride) ((float4*)p1)[k] = z;
}

// ---- CSR build ----
__global__ void k_cnt(const int* __restrict__ eidx, int* __restrict__ cnt) {
    int e = blockIdx.x * 256 + threadIdx.x;
    if (e < NE) atomicAdd(&cnt[eidx[e]], 1);
}

__global__ __launch_bounds__(256) void k_scan1(const int* __restrict__ cnt,
                                               int* __restrict__ offw,
                                               int* __restrict__ bsum) {
    __shared__ int sw_[4];
    int i = blockIdx.x * 256 + threadIdx.x;
    int lane = threadIdx.x & 63, wv = threadIdx.x >> 6;
    int v = (i < NN) ? cnt[i] : 0;
    int inc = v;
    #pragma unroll
    for (int d = 1; d < 64; d <<= 1) {
        int t = __shfl_up(inc, d, 64);
        if (lane >= d) inc += t;
    }
    if (lane == 63) sw_[wv] = inc;
    __syncthreads();
    int woff = 0;
    #pragma unroll
    for (int k = 0; k < 4; ++k) woff += (k < wv) ? sw_[k] : 0;
    if (i < NN) offw[i] = woff + inc - v;
    if (threadIdx.x == 255) bsum[blockIdx.x] = woff + inc;
}

__global__ __launch_bounds__(256) void k_scan2(int* __restrict__ bsum, int nb) {
    __shared__ int sw_[4];
    int t = threadIdx.x;
    int lane = t & 63, wv = t >> 6;
    int v = (t < nb) ? bsum[t] : 0;
    int inc = v;
    #pragma unroll
    for (int d = 1; d < 64; d <<= 1) {
        int s = __shfl_up(inc, d, 64);
        if (lane >= d) inc += s;
    }
    if (lane == 63) sw_[wv] = inc;
    __syncthreads();
    int woff = 0;
    #pragma unroll
    for (int k = 0; k < 4; ++k) woff += (k < wv) ? sw_[k] : 0;
    if (t < nb) bsum[t] = woff + inc - v;
}

__global__ void k_scan3(int* __restrict__ offw, const int* __restrict__ bsum,
                        int* __restrict__ rowptr) {
    int i = blockIdx.x * 256 + threadIdx.x;
    if (i < NN) {
        int v = offw[i] + bsum[blockIdx.x];
        offw[i] = v;
        rowptr[i] = v;
    }
    if (i == 0) rowptr[NN] = NE;
}

// ---- scatter: physically permute edges into row-sorted order (bf16 ea_s) ----
__global__ void k_scatter(const int* __restrict__ eidx, const float* __restrict__ ea,
                          int* __restrict__ offw, short* __restrict__ ea_s,
                          int* __restrict__ col_s, int* __restrict__ row_s) {
    int e = blockIdx.x * 256 + threadIdx.x;
    if (e >= NE) return;
    int r = eidx[e], c = eidx[NE + e];
    int pos = atomicAdd(&offw[r], 1);
    col_s[pos] = c;
    row_s[pos] = r;
    const float4* src = (const float4*)(ea + (size_t)e * ECH);
    short* dst = ea_s + (size_t)pos * ECH;
    #pragma unroll
    for (int i = 0; i < 4; ++i) {
        float4 f0 = src[4 * i], f1 = src[4 * i + 1], f2 = src[4 * i + 2], f3 = src[4 * i + 3];
        u32x4 v0 = {cvtpk(f0.x, f0.y), cvtpk(f0.z, f0.w), cvtpk(f1.x, f1.y), cvtpk(f1.z, f1.w)};
        u32x4 v1 = {cvtpk(f2.x, f2.y), cvtpk(f2.z, f2.w), cvtpk(f3.x, f3.y), cvtpk(f3.z, f3.w)};
        *(u32x4*)(dst + i * 16) = v0;
        *(u32x4*)(dst + i * 16 + 8) = v1;
    }
}

// ---- K1: h[N,256] = x @ Wl1 (MFMA), h stored in p-order ----
__global__ __launch_bounds__(256) void k1_h(const float* __restrict__ x,
                                            const short* __restrict__ pW,
                                            short* __restrict__ h) {
    __shared__ char xS[32 * 256];   // [32][128] bf16, swizzled
    int n0 = blockIdx.x * 32;
    int tid = threadIdx.x;
    int lane = tid & 63, w = tid >> 6, q = lane >> 4, l15 = lane & 15;
    {
        int r = tid >> 3, seg = tid & 7;
        int rr = min(n0 + r, NN - 1);
        const float4* src = (const float4*)(x + (size_t)rr * CC + seg * 16);
        float4 f0 = src[0], f1 = src[1], f2 = src[2], f3 = src[3];
        u32x4 c0 = {cvtpk(f0.x, f0.y), cvtpk(f0.z, f0.w), cvtpk(f1.x, f1.y), cvtpk(f1.z, f1.w)};
        u32x4 c1 = {cvtpk(f2.x, f2.y), cvtpk(f2.z, f2.w), cvtpk(f3.x, f3.y), cvtpk(f3.z, f3.w)};
        int sw = (r & 7) << 4;
        *(u32x4*)(xS + r * 256 + ((seg * 32) ^ sw)) = c0;
        *(u32x4*)(xS + r * 256 + ((seg * 32 + 16) ^ sw)) = c1;
    }
    __syncthreads();

    f32x4 acc[2][4];
    #pragma unroll
    for (int mf = 0; mf < 2; ++mf)
        #pragma unroll
        for (int nf = 0; nf < 4; ++nf) acc[mf][nf] = f32x4{0.f, 0.f, 0.f, 0.f};

    #pragma unroll
    for (int ks = 0; ks < 4; ++ks) {
        bf16x8 a[2];
        #pragma unroll
        for (int mf = 0; mf < 2; ++mf) {
            int row = mf * 16 + l15;
            a[mf] = *(const bf16x8*)(xS + row * 256 + ((ks * 64 + q * 16) ^ ((row & 7) << 4)));
        }
        #pragma unroll
        for (int nf = 0; nf < 4; ++nf) {
            bf16x8 b = *(const bf16x8*)(pW + PO_WL1 + (((ks * 16 + w * 4 + nf) * 64) + lane) * 8);
            #pragma unroll
            for (int mf = 0; mf < 2; ++mf)
                acc[mf][nf] = __builtin_amdgcn_mfma_f32_16x16x32_bf16(a[mf], b, acc[mf][nf], 0, 0, 0);
        }
    }
    #pragma unroll
    for (int mf = 0; mf < 2; ++mf) {
        #pragma unroll
        for (int r = 0; r < 4; ++r) {
            int n = n0 + mf * 16 + q * 4 + r;
            if (n < NN) {
                u32x2 v = {cvtpk(acc[mf][0][r], acc[mf][1][r]),
                           cvtpk(acc[mf][2][r], acc[mf][3][r])};
                *(u32x2*)(h + (size_t)n * NFF + w * 64 + l15 * 4) = v;
            }
        }
    }
}

// ---- K2b: FUSED filter-net + modulate + in-LDS segment-reduce -> agg fp32 ----
// 64 sorted slots/block, 4 waves; wave w owns cols [w*64, w*64+64).
// Walk: ALL 256 threads; 2 threads per col-pair, 32 slots each.
__global__ __launch_bounds__(256, 4) void k2b_agg(
        const short* __restrict__ ea_s, const int* __restrict__ col_s,
        const int* __restrict__ row_s,
        const short* __restrict__ pW, const float* __restrict__ bf1v,
        const float* __restrict__ bf2v,
        const short* __restrict__ h, float* __restrict__ agg) {
    __shared__ char t1S[64 * 512];   // t1 p-order -> h rows -> msg tile (in place)
    __shared__ int colS[64], rowS[64];
    int s0 = blockIdx.x * 64;
    int tid = threadIdx.x;
    int lane = tid & 63, w = tid >> 6;
    int q = lane >> 4, l15 = lane & 15;

    if (tid < 64) {
        colS[tid] = col_s[s0 + tid];
        rowS[tid] = row_s[s0 + tid];
    }

    f32x4 acc[4][4];
    #pragma unroll
    for (int mf = 0; mf < 4; ++mf)
        #pragma unroll
        for (int nf = 0; nf < 4; ++nf) acc[mf][nf] = f32x4{0.f, 0.f, 0.f, 0.f};

    // phase 1: t1 = ssp(ea_s @ Wf1 + b1), K=64, M=64; A direct from global bf16
    #pragma unroll
    for (int ks = 0; ks < 2; ++ks) {
        bf16x8 a[4];
        #pragma unroll
        for (int mf = 0; mf < 4; ++mf)
            a[mf] = *(const bf16x8*)(ea_s + (size_t)(s0 + mf * 16 + l15) * ECH + ks * 32 + q * 8);
        #pragma unroll
        for (int nf = 0; nf < 4; ++nf) {
            bf16x8 b = *(const bf16x8*)(pW + PO_WF1 + (((ks * 16 + w * 4 + nf) * 64) + lane) * 8);
            #pragma unroll
            for (int mf = 0; mf < 4; ++mf)
                acc[mf][nf] = __builtin_amdgcn_mfma_f32_16x16x32_bf16(a[mf], b, acc[mf][nf], 0, 0, 0);
        }
    }
    // ssp + bias, write t1 in p-order: b64 per (mf,r)
    {
        float bia[4];
        #pragma unroll
        for (int nf = 0; nf < 4; ++nf) bia[nf] = bf1v[w * 64 + nf * 16 + l15];
        #pragma unroll
        for (int mf = 0; mf < 4; ++mf) {
            #pragma unroll
            for (int r = 0; r < 4; ++r) {
                int row = mf * 16 + q * 4 + r;
                u32x2 v = {cvtpk(sspf(acc[mf][0][r] + bia[0]), sspf(acc[mf][1][r] + bia[1])),
                           cvtpk(sspf(acc[mf][2][r] + bia[2]), sspf(acc[mf][3][r] + bia[3]))};
                *(u32x2*)(t1S + row * 512 + ((w * 128 + l15 * 8) ^ ((row & 7) << 4))) = v;
            }
        }
    }
    __syncthreads();

    #pragma unroll
    for (int mf = 0; mf < 4; ++mf)
        #pragma unroll
        for (int nf = 0; nf < 4; ++nf) acc[mf][nf] = f32x4{0.f, 0.f, 0.f, 0.f};

    // phase 2: Wf = t1 @ Wf2 + b2, K=256, M=64 (k in p-order)
    for (int ks = 0; ks < 8; ++ks) {
        bf16x8 a[4];
        #pragma unroll
        for (int mf = 0; mf < 4; ++mf) {
            int row = mf * 16 + l15;
            a[mf] = *(const bf16x8*)(t1S + row * 512 + ((ks * 64 + q * 16) ^ ((row & 7) << 4)));
        }
        #pragma unroll
        for (int nf = 0; nf < 4; ++nf) {
            bf16x8 b = *(const bf16x8*)(pW + PO_WF2 + (((ks * 16 + w * 4 + nf) * 64) + lane) * 8);
            #pragma unroll
            for (int mf = 0; mf < 4; ++mf)
                acc[mf][nf] = __builtin_amdgcn_mfma_f32_16x16x32_bf16(a[mf], b, acc[mf][nf], 0, 0, 0);
        }
    }
    __syncthreads();   // t1S reads done; reuse region for h rows

    {   // stage h[colS[0..63]] (p-order rows) into LDS: 4 thr/row, 8x16B each
        int r = tid >> 2, ch = tid & 3;
        const short* hp = h + (size_t)colS[r] * NFF;
        int sw = (r & 7) << 4;
        #pragma unroll
        for (int i = 0; i < 8; ++i) {
            int chunk = ch + i * 4;
            bf16x8 v = *(const bf16x8*)(hp + chunk * 8);
            *(bf16x8*)(t1S + r * 512 + ((chunk * 16) ^ sw)) = v;
        }
    }
    __syncthreads();

    // in-place modulate: t1S[eloc][p-pair] = h * Wf  (each addr owned by one thread)
    {
        float bia[4];
        #pragma unroll
        for (int nf = 0; nf < 4; ++nf) bia[nf] = bf2v[w * 64 + nf * 16 + l15];
        #pragma unroll
        for (int mf = 0; mf < 4; ++mf) {
            #pragma unroll
            for (int r = 0; r < 4; ++r) {
                int eloc = mf * 16 + q * 4 + r;
                char* addr = t1S + eloc * 512 + ((w * 128 + l15 * 8) ^ ((eloc & 7) << 4));
                u32x2 hv = *(const u32x2*)addr;
                float m0 = bfu_lo(hv[0]) * (acc[mf][0][r] + bia[0]);
                float m1 = bfu_hi(hv[0]) * (acc[mf][1][r] + bia[1]);
                float m2 = bfu_lo(hv[1]) * (acc[mf][2][r] + bia[2]);
                float m3 = bfu_hi(hv[1]) * (acc[mf][3][r] + bia[3]);
                u32x2 out = {cvtpk(m0, m1), cvtpk(m2, m3)};
                *(u32x2*)addr = out;
            }
        }
    }
    __syncthreads();

    // segment-reduce: ALL 256 threads. thread = (half, cp): cp = tid&127 owns
    // cols (2cp, 2cp+1) in p-order; half = tid>>7 walks slots [half*32, half*32+32).
    // Segment fully interior to the sub-range -> exactly-once direct store;
    // segment touching a sub-range boundary -> atomicAdd onto the zeroed base.
    {
        int cp = tid & 127;
        int h0 = (tid >> 7) * 32;
        float a0 = 0.f, a1 = 0.f;
        int cur = rowS[h0];
        bool first = true;
        for (int e = h0; e < h0 + 32; ++e) {
            int rw = rowS[e];
            if (rw != cur) {
                float* dst = agg + (size_t)cur * NFF + cp * 2;
                if (first) { atomicAdd(dst, a0); atomicAdd(dst + 1, a1); first = false; }
                else       { dst[0] = a0; dst[1] = a1; }
                a0 = 0.f; a1 = 0.f;
                cur = rw;
            }
            unsigned v = *(const unsigned*)(t1S + e * 512 + ((cp * 4) ^ ((e & 7) << 4)));
            a0 += bfu_lo(v);
            a1 += bfu_hi(v);
        }
        // last segment of the sub-range: always boundary
        float* dst = agg + (size_t)cur * NFF + cp * 2;
        atomicAdd(dst, a0); atomicAdd(dst + 1, a1);
    }
}

// ---- K3: load agg (fp32, p-order) + MFMA node GEMMs ----
__global__ __launch_bounds__(256) void k3_node(
        const float* __restrict__ agg,
        const short* __restrict__ pW, const float* __restrict__ bl2,
        const float* __restrict__ bl3,
        const float* __restrict__ x, float* __restrict__ xo) {
    __shared__ char aggS[32 * 512];  // [32][256] bf16 p-order, swizzled
    __shared__ char t2S[32 * 256];   // [32][128] bf16 p2-order, swizzled
    int n0 = blockIdx.x * 32;
    int tid = threadIdx.x;
    int lane = tid & 63, w = tid >> 6, q = lane >> 4, l15 = lane & 15;

    {   // coalesced agg load: 8 thr/node, 32 cols each
        int nd = tid >> 3, c0 = (tid & 7) * 32;
        int n = n0 + nd;
        float a[32];
        if (n < NN) {
            const float4* src = (const float4*)(agg + (size_t)n * NFF + c0);
            #pragma unroll
            for (int j = 0; j < 8; ++j) {
                float4 v = src[j];
                a[4 * j] = v.x; a[4 * j + 1] = v.y; a[4 * j + 2] = v.z; a[4 * j + 3] = v.w;
            }
        } else {
            #pragma unroll
            for (int i = 0; i < 32; ++i) a[i] = 0.f;
        }
        int sw = (nd & 7) << 4;
        #pragma unroll
        for (int j = 0; j < 4; ++j) {
            u32x4 v = {cvtpk(a[j * 8 + 0], a[j * 8 + 1]), cvtpk(a[j * 8 + 2], a[j * 8 + 3]),
                       cvtpk(a[j * 8 + 4], a[j * 8 + 5]), cvtpk(a[j * 8 + 6], a[j * 8 + 7])};
            *(u32x4*)(aggS + nd * 512 + (((c0 + j * 8) * 2) ^ sw)) = v;
        }
    }
    __syncthreads();

    // GEMM1: t2 = ssp(agg @ Wl2 + b2), k in p-order (pWl2 matches)
    f32x4 acc[2][2];
    #pragma unroll
    for (int mf = 0; mf < 2; ++mf)
        #pragma unroll
        for (int nf = 0; nf < 2; ++nf) acc[mf][nf] = f32x4{0.f, 0.f, 0.f, 0.f};
    for (int ks = 0; ks < 8; ++ks) {
        bf16x8 a[2];
        #pragma unroll
        for (int mf = 0; mf < 2; ++mf) {
            int row = mf * 16 + l15;
            a[mf] = *(const bf16x8*)(aggS + row * 512 + ((ks * 64 + q * 16) ^ ((row & 7) << 4)));
        }
        #pragma unroll
        for (int nf = 0; nf < 2; ++nf) {
            bf16x8 b = *(const bf16x8*)(pW + PO_WL2 + (((ks * 8 + w * 2 + nf) * 64) + lane) * 8);
            #pragma unroll
            for (int mf = 0; mf < 2; ++mf)
                acc[mf][nf] = __builtin_amdgcn_mfma_f32_16x16x32_bf16(a[mf], b, acc[mf][nf], 0, 0, 0);
        }
    }
    {   // t2 in p2-order: b32 per (mf,r)
        float bia[2];
        #pragma unroll
        for (int nf = 0; nf < 2; ++nf) bia[nf] = bl2[w * 32 + nf * 16 + l15];
        #pragma unroll
        for (int mf = 0; mf < 2; ++mf) {
            #pragma unroll
            for (int r = 0; r < 4; ++r) {
                int row = mf * 16 + q * 4 + r;
                unsigned u = cvtpk(sspf(acc[mf][0][r] + bia[0]), sspf(acc[mf][1][r] + bia[1]));
                *(unsigned*)(t2S + row * 256 + ((w * 64 + l15 * 4) ^ ((row & 7) << 4))) = u;
            }
        }
    }
    __syncthreads();

    // GEMM2: y = t2 @ Wl3 + b3, k in p2-order (pWl3 matches)
    f32x4 acc2[2][2];
    #pragma unroll
    for (int mf = 0; mf < 2; ++mf)
        #pragma unroll
        for (int nf = 0; nf < 2; ++nf) acc2[mf][nf] = f32x4{0.f, 0.f, 0.f, 0.f};
    #pragma unroll
    for (int ks = 0; ks < 4; ++ks) {
        bf16x8 a[2];
        #pragma unroll
        for (int mf = 0; mf < 2; ++mf) {
            int row = mf * 16 + l15;
            a[mf] = *(const bf16x8*)(t2S + row * 256 + ((ks * 64 + q * 16) ^ ((row & 7) << 4)));
        }
        #pragma unroll
        for (int nf = 0; nf < 2; ++nf) {
            bf16x8 b = *(const bf16x8*)(pW + PO_WL3 + (((ks * 8 + w * 2 + nf) * 64) + lane) * 8);
            #pragma unroll
            for (int mf = 0; mf < 2; ++mf)
                acc2[mf][nf] = __builtin_amdgcn_mfma_f32_16x16x32_bf16(a[mf], b, acc2[mf][nf], 0, 0, 0);
        }
    }
    #pragma unroll
    for (int nf = 0; nf < 2; ++nf) {
        int col = w * 32 + nf * 16 + l15;
        float bias = bl3[col];
        #pragma unroll
        for (int mf = 0; mf < 2; ++mf) {
            #pragma unroll
            for (int r = 0; r < 4; ++r) {
                int n = n0 + mf * 16 + q * 4 + r;
                if (n < NN) {
                    size_t o = (size_t)n * CC + col;
                    xo[o] = fmaxf(acc2[mf][nf][r] + bias, 0.f) + x[o];
                }
            }
        }
    }
}

// ---- K4: MFMA e_out = tanh([ea | xo[row]+xo[col]] @ We + be) ----
__global__ __launch_bounds__(256) void k4_mfma(
        const float* __restrict__ ea, const int* __restrict__ eidx,
        const float* __restrict__ xo, const short* __restrict__ pW,
        const float* __restrict__ bev, float* __restrict__ eo) {
    __shared__ char aS[64 * 384];    // [64][192] bf16, swizzled
    int e0 = blockIdx.x * 64;
    int tid = threadIdx.x;
    int lane = tid & 63, w = tid >> 6;
    int q = lane >> 4, l15 = lane & 15;

    {   // stage ea (k 0..63)
        int r = tid >> 2, cp = tid & 3;
        const float4* src = (const float4*)(ea + (size_t)(e0 + r) * ECH + cp * 16);
        float4 f0 = src[0], f1 = src[1], f2 = src[2], f3 = src[3];
        u32x4 c0 = {cvtpk(f0.x, f0.y), cvtpk(f0.z, f0.w), cvtpk(f1.x, f1.y), cvtpk(f1.z, f1.w)};
        u32x4 c1 = {cvtpk(f2.x, f2.y), cvtpk(f2.z, f2.w), cvtpk(f3.x, f3.y), cvtpk(f3.z, f3.w)};
        int sw = (r & 7) << 4;
        *(u32x4*)(aS + r * 384 + ((cp * 32) ^ sw)) = c0;
        *(u32x4*)(aS + r * 384 + ((cp * 32 + 16) ^ sw)) = c1;
    }
    {   // stage xo[row]+xo[col] (k 64..191)
        int e = tid >> 2, p = tid & 3;
        int rr = eidx[e0 + e], cc = eidx[NE + e0 + e];
        const float4* xr = (const float4*)(xo + (size_t)rr * CC);
        const float4* xc = (const float4*)(xo + (size_t)cc * CC);
        int sw = (e & 7) << 4;
        #pragma unroll
        for (int it = 0; it < 8; ++it) {
            int fi = p + it * 4;
            float4 va = xr[fi], vb = xc[fi];
            u32x2 hv = {cvtpk(va.x + vb.x, va.y + vb.y), cvtpk(va.z + vb.z, va.w + vb.w)};
            int byte = (ECH + fi * 4) * 2;
            *(u32x2*)(aS + e * 384 + (byte ^ sw)) = hv;
        }
    }
    __syncthreads();

    f32x4 acc[8];
    #pragma unroll
    for (int nf = 0; nf < 8; ++nf) acc[nf] = f32x4{0.f, 0.f, 0.f, 0.f};

    #pragma unroll
    for (int ks = 0; ks < 6; ++ks) {
        int row = w * 16 + l15;
        bf16x8 a = *(const bf16x8*)(aS + row * 384 + ((ks * 64 + q * 16) ^ ((row & 7) << 4)));
        #pragma unroll
        for (int nf = 0; nf < 8; ++nf) {
            bf16x8 b = *(const bf16x8*)(pW + PO_WE + (((ks * 8 + nf) * 64) + lane) * 8);
            acc[nf] = __builtin_amdgcn_mfma_f32_16x16x32_bf16(a, b, acc[nf], 0, 0, 0);
        }
    }
    #pragma unroll
    for (int nf = 0; nf < 8; ++nf) {
        int col = nf * 16 + l15;
        float bias = bev[col];
        #pragma unroll
        for (int r = 0; r < 4; ++r) {
            int e = e0 + w * 16 + q * 4 + r;
            eo[(size_t)e * CC + col] = ftanh(acc[nf][r] + bias);
        }
    }
}

extern "C" void kernel_launch(void* const* d_in, const int* in_sizes, int n_in,
                              void* d_out, int out_size, void* d_ws, size_t ws_size,
                              hipStream_t stream) {
    const float* x   = (const float*)d_in[0];
    const int*   ei  = (const int*)d_in[1];
    const float* ea  = (const float*)d_in[2];
    const float* Wf1 = (const float*)d_in[4];
    const float* bf1 = (const float*)d_in[5];
    const float* Wf2 = (const float*)d_in[6];
    const float* bf2 = (const float*)d_in[7];
    const float* Wl1 = (const float*)d_in[8];
    const float* Wl2 = (const float*)d_in[9];
    const float* bl2 = (const float*)d_in[10];
    const float* Wl3 = (const float*)d_in[11];
    const float* bl3 = (const float*)d_in[12];
    const float* We  = (const float*)d_in[13];
    const float* be  = (const float*)d_in[14];

    float* xo = (float*)d_out;                 // [N, C] final
    float* eo = xo + (size_t)NN * CC;          // [E, C] final

    // region reuse (sequential lifetimes, fully rewritten each call):
    //   h    bf16 [N,256] p-order in the xo region (dead before k3 writes xo)
    //   ea_s/col_s/row_s/agg carved from the TAIL of the eo region
    //   (all dead before k4 writes eo; k3 reads agg before k4 runs)
    short* h    = (short*)xo;                                  // 25.6 MB
    char*  top  = (char*)d_out + (size_t)out_size * sizeof(float);
    short* ea_s = (short*)(top - (size_t)NE * ECH * 2);        // 76.8 MB
    int*   col_s = (int*)((char*)ea_s - (size_t)NE * 4);       // 2.4 MB
    int*   row_s = (int*)((char*)col_s - (size_t)NE * 4);      // 2.4 MB
    float* agg  = (float*)((char*)row_s - (size_t)NN * NFF * 4); // 51.2 MB

    // ws: [packed weights 384KB][cnt N][offw N][rowptr N+1][bsum 256]
    short* pW    = (short*)d_ws;
    int* cnt     = (int*)((char*)d_ws + 393216);
    int* offw    = cnt + NN;
    int* rowptr  = offw + NN;
    int* bsum    = rowptr + NN + 1;

    const int NB = (NN + 255) / 256;

    kpack<<<P_TOT / 256, 256, 0, stream>>>(Wf1, Wf2, We, Wl1, Wl2, Wl3, pW);
    k0_zero2<<<1024, 256, 0, stream>>>(agg, (long)NN * NFF / 4, (float*)cnt, NN / 4);
    k_cnt<<<(NE + 255) / 256, 256, 0, stream>>>(ei, cnt);
    k_scan1<<<NB, 256, 0, stream>>>(cnt, offw, bsum);
    k_scan2<<<1, 256, 0, stream>>>(bsum, NB);
    k_scan3<<<NB, 256, 0, stream>>>(offw, bsum, rowptr);
    k_scatter<<<(NE + 255) / 256, 256, 0, stream>>>(ei, ea, offw, ea_s, col_s, row_s);
    k1_h<<<(NN + 31) / 32, 256, 0, stream>>>(x, pW, h);
    k2b_agg<<<NE / 64, 256, 0, stream>>>(ea_s, col_s, row_s, pW, bf1, bf2, h, agg);
    k3_node<<<(NN + 31) / 32, 256, 0, stream>>>(agg, pW, bl2, bl3, x, xo);
    k4_mfma<<<NE / 64, 256, 0, stream>>>(ea, ei, xo, pW, be, eo);
}